// Round 1
// baseline (2012.652 us; speedup 1.0000x reference)
//
#include <hip/hip_runtime.h>
#include <math.h>

// ---------------- helpers ----------------
__device__ __forceinline__ float sigm(float x){ return 1.f/(1.f+__expf(-x)); }
__device__ __forceinline__ float tanhx(float x){
  x = fminf(fmaxf(x,-15.f),15.f);
  float e = __expf(2.f*x);
  return (e-1.f)/(e+1.f);
}

// ---------------- workspace layout (floats) ----------------
#define O_CNN    0            // 2048*96
#define O_CLSTM  196608       // 2048*100
#define O_FUSED  401408       // 2048*200
#define O_XG2    811008       // 2*2048*512
#define O_LSTM   2908160      // 2048*256
#define O_WJ     3432448      // 2048
#define O_CTXB   3434496      // 2048*256
#define O_EM     3958784      // 256*8*11
#define O_NLL    3981312      // 8
#define O_FWT    3981320      // 396*200
#define O_CWIHT  4060520      // 200*1024
#define O_CWHHT  4265320      // 128*1024
#define O_LWIHT  4396392      // 50*400
#define O_LWHHT  4416392      // 50*400
#define O_PWT    4436392      // 512*256
#define WS_TOTAL 4567464

// ---------------- K0: transpose all weight matrices ----------------
__global__ __launch_bounds__(256) void k_transpose(
    const float* __restrict__ fusion_w,
    const float* __restrict__ cwih_f, const float* __restrict__ cwih_b,
    const float* __restrict__ cwhh_f, const float* __restrict__ cwhh_b,
    const float* __restrict__ lwih_f, const float* __restrict__ lwih_b,
    const float* __restrict__ lwhh_f, const float* __restrict__ lwhh_b,
    const float* __restrict__ proj_w,
    float* __restrict__ fwT, float* __restrict__ cwihT, float* __restrict__ cwhhT,
    float* __restrict__ lwihT, float* __restrict__ lwhhT, float* __restrict__ pwT)
{
  int id = blockIdx.x*256 + threadIdx.x;
  if (id < 79200) {                              // fusion_w [200,396] -> [396][200]
    int jr = id/396, d = id-jr*396;
    fwT[d*200 + jr] = fusion_w[id];
    return;
  }
  id -= 79200;
  if (id < 204800) {                             // ctx wih [512,200]x2 -> [200][1024]
    int dir = id/102400, e = id%102400;
    int r = e/200, d = e-r*200;
    cwihT[d*1024 + dir*512 + r] = (dir? cwih_b : cwih_f)[e];
    return;
  }
  id -= 204800;
  if (id < 131072) {                             // ctx whh [512,128]x2 -> [128][1024]
    int dir = id>>16, e = id&65535;
    int r = e>>7, d = e&127;
    cwhhT[d*1024 + dir*512 + r] = (dir? cwhh_b : cwhh_f)[e];
    return;
  }
  id -= 131072;
  if (id < 20000) {                              // clstm wih [200,50]x2 -> [50][400]
    int dir = id/10000, e = id%10000;
    int jr = e/50, i = e-jr*50;
    lwihT[i*400 + dir*200 + jr] = (dir? lwih_b : lwih_f)[e];
    return;
  }
  id -= 20000;
  if (id < 20000) {                              // clstm whh [200,50]x2 -> [50][400]
    int dir = id/10000, e = id%10000;
    int jr = e/50, i = e-jr*50;
    lwhhT[i*400 + dir*200 + jr] = (dir? lwhh_b : lwhh_f)[e];
    return;
  }
  id -= 20000;
  if (id < 131072) {                             // proj_w [256,512] -> [512][256]
    int jr = id>>9, d = id&511;
    pwT[d*256 + jr] = proj_w[id];
  }
}

// ---------------- K1: char CNN (per-token block) ----------------
__global__ __launch_bounds__(384) void k_charcnn(
    const int* __restrict__ char_ids, const float* __restrict__ ctab,
    const float* __restrict__ w3, const float* __restrict__ b3,
    const float* __restrict__ w5, const float* __restrict__ b5,
    const float* __restrict__ w7, const float* __restrict__ b7,
    float* __restrict__ cnn_feat)
{
  __shared__ float ce[16*52];
  int n = blockIdx.x, tid = threadIdx.x;
  for (int e=tid; e<16*52; e+=384) {
    int t = e/52, i = e-52*t;
    ce[e] = (i<50) ? ctab[char_ids[n*16+t]*50 + i] : 0.f;
  }
  __syncthreads();
  int g = tid>>7, r = tid&127, o = r>>2, iq = r&3;
  const float* w  = (g==0)? w3 : ((g==1)? w5 : w7);
  const float* bb = (g==0)? b3 : ((g==1)? b5 : b7);
  int K = (g==0)?3:((g==1)?5:7);
  int i0 = iq*13, i1 = min(50, i0+13);
  float acc[16];
  #pragma unroll
  for (int p=0;p<16;p++) acc[p]=0.f;
  for (int i=i0;i<i1;i++) {
    float col[16];
    #pragma unroll
    for (int t=0;t<16;t++) col[t] = ce[t*52+i];
    for (int t=0;t<K;t++) {
      float wv = w[(o*50+i)*K + t];
      int sh = t - (K>>1);
      #pragma unroll
      for (int p=0;p<16;p++) {
        int pos = p+sh;
        if (pos>=0 && pos<16) acc[p] += wv*col[pos];
      }
    }
  }
  #pragma unroll
  for (int p=0;p<16;p++) { acc[p] += __shfl_xor(acc[p],1); acc[p] += __shfl_xor(acc[p],2); }
  if (iq==0) {
    float bias = bb[o];
    float m = 0.f;   // relu then max over positions = max(0, max_p y)
    #pragma unroll
    for (int p=0;p<16;p++) m = fmaxf(m, acc[p]+bias);
    cnn_feat[n*96 + g*32 + o] = m;
  }
}

// ---------------- K2: char BiLSTM (per (token, dir) block), max over time ----------------
__global__ __launch_bounds__(256) void k_charlstm(
    const int* __restrict__ char_ids, const float* __restrict__ ctab,
    const float* __restrict__ lwihT, const float* __restrict__ lwhhT,
    const float* __restrict__ b_f, const float* __restrict__ b_b,
    float* __restrict__ clstm_feat)
{
  __shared__ alignas(16) float ce[16*52];
  __shared__ alignas(16) float hbuf[64];
  __shared__ float gates[200];
  int n = blockIdx.x, dir = blockIdx.y, tid = threadIdx.x;
  for (int e=tid; e<16*52; e+=256) {
    int t = e/52, i = e-52*t;
    int tt = dir ? 15-t : t;
    ce[e] = (i<50) ? ctab[char_ids[n*16+tt]*50 + i] : 0.f;
  }
  if (tid<64) hbuf[tid]=0.f;
  __syncthreads();
  int j = tid;
  float wr[52];
  float xg[16];
  if (j<200) {
    #pragma unroll
    for (int i=0;i<50;i++) wr[i] = lwihT[i*400 + dir*200 + j];
    wr[50]=0.f; wr[51]=0.f;
    float bj = (dir? b_b : b_f)[j];
    #pragma unroll
    for (int t=0;t<16;t++) xg[t]=bj;
    #pragma unroll
    for (int i4=0;i4<13;i4++) {
      float w0=wr[4*i4], w1=wr[4*i4+1], w2=wr[4*i4+2], w3v=wr[4*i4+3];
      #pragma unroll
      for (int t=0;t<16;t++) {
        const float4 c4 = *(const float4*)&ce[t*52 + 4*i4];
        xg[t] += w0*c4.x + w1*c4.y + w2*c4.z + w3v*c4.w;
      }
    }
    #pragma unroll
    for (int i=0;i<50;i++) wr[i] = lwhhT[i*400 + dir*200 + j];
  }
  float cst=0.f, m=-1e30f;
  __syncthreads();
  for (int t=0;t<16;t++) {
    if (j<200) {
      float gsum = xg[t];
      #pragma unroll
      for (int i4=0;i4<13;i4++) {
        const float4 h4 = *(const float4*)&hbuf[4*i4];
        gsum += wr[4*i4]*h4.x + wr[4*i4+1]*h4.y + wr[4*i4+2]*h4.z + wr[4*i4+3]*h4.w;
      }
      gates[j] = gsum;
    }
    __syncthreads();
    if (j<50) {
      float gi=gates[j], gf=gates[50+j], gc=gates[100+j], go=gates[150+j];
      cst = sigm(gf)*cst + sigm(gi)*tanhx(gc);
      float h = sigm(go)*tanhx(cst);
      m = fmaxf(m,h);
      hbuf[j]=h;
    }
    __syncthreads();
  }
  if (j<50) clstm_feat[n*100 + dir*50 + j] = m;
}

// ---------------- K3: fusion linear (8 tokens / block) ----------------
__global__ __launch_bounds__(256) void k_fusion(
    const int* __restrict__ word_ids, const float* __restrict__ wtab,
    const float* __restrict__ cnn_feat, const float* __restrict__ clstm_feat,
    const float* __restrict__ fwT, const float* __restrict__ fusion_b,
    float* __restrict__ fused)
{
  __shared__ alignas(16) float combT[400*8];
  int n0 = blockIdx.x*8, tid = threadIdx.x;
  for (int e=tid; e<3200; e+=256) {
    int d = e>>3, tok = e&7;
    int n = n0+tok;
    float v;
    if (d<200) v = wtab[word_ids[n]*200 + d];
    else if (d<296) v = cnn_feat[n*96 + d-200];
    else if (d<396) v = clstm_feat[n*100 + d-296];
    else v = 0.f;
    combT[e] = v;
  }
  __syncthreads();
  int j = tid;
  if (j<200) {
    float acc[8];
    float bj = fusion_b[j];
    #pragma unroll
    for (int t=0;t<8;t++) acc[t]=bj;
    for (int d=0; d<396; d++) {
      float w = fwT[d*200 + j];
      const float4 c0 = *(const float4*)&combT[d*8];
      const float4 c1 = *(const float4*)&combT[d*8+4];
      acc[0]+=w*c0.x; acc[1]+=w*c0.y; acc[2]+=w*c0.z; acc[3]+=w*c0.w;
      acc[4]+=w*c1.x; acc[5]+=w*c1.y; acc[6]+=w*c1.z; acc[7]+=w*c1.w;
    }
    #pragma unroll
    for (int t=0;t<8;t++) fused[(n0+t)*200 + j] = acc[t];
  }
}

// ---------------- K4: ctx LSTM input gates xg = fused @ WihT + b (both dirs) ----------------
__global__ __launch_bounds__(256) void k_ctxxg(
    const float* __restrict__ fused, const float* __restrict__ cwihT,
    const float* __restrict__ bf, const float* __restrict__ bbw,
    float* __restrict__ xg2)
{
  __shared__ alignas(16) float fuT[200*8];
  int n0 = blockIdx.x*8, tid = threadIdx.x;
  for (int e=tid; e<1600; e+=256) {
    int d = e>>3, tok = e&7;
    fuT[e] = fused[(n0+tok)*200 + d];
  }
  __syncthreads();
  int j = tid;
  float acc[4][8];
  #pragma unroll
  for (int s=0;s<4;s++) {
    int dir = s>>1, rr = (s&1)*256 + j;
    float bv = (dir? bbw : bf)[rr];
    #pragma unroll
    for (int t=0;t<8;t++) acc[s][t]=bv;
  }
  for (int d=0; d<200; d++) {
    float w0 = cwihT[d*1024 + j];
    float w1 = cwihT[d*1024 + 256 + j];
    float w2 = cwihT[d*1024 + 512 + j];
    float w3v= cwihT[d*1024 + 768 + j];
    const float4 f0 = *(const float4*)&fuT[d*8];
    const float4 f1 = *(const float4*)&fuT[d*8+4];
    float fv[8] = {f0.x,f0.y,f0.z,f0.w,f1.x,f1.y,f1.z,f1.w};
    #pragma unroll
    for (int t=0;t<8;t++) {
      acc[0][t]+=w0*fv[t]; acc[1][t]+=w1*fv[t]; acc[2][t]+=w2*fv[t]; acc[3][t]+=w3v*fv[t];
    }
  }
  #pragma unroll
  for (int s=0;s<4;s++) {
    int dir = s>>1, rr = (s&1)*256 + j;
    #pragma unroll
    for (int t=0;t<8;t++)
      xg2[((size_t)dir*2048 + n0+t)*512 + rr] = acc[s][t];
  }
}

// ---------------- K5: context BiLSTM recurrence (16 blocks: (b,dir)) ----------------
__global__ __launch_bounds__(512) void k_ctxlstm(
    const float* __restrict__ xg2, const float* __restrict__ cwhhT,
    float* __restrict__ lstm_out)
{
  __shared__ alignas(16) float hbuf[128];
  __shared__ float gates[512];
  int u = blockIdx.x;
  int b = u&7, dir = u>>3;
  int j = threadIdx.x;
  float wr[128];
  #pragma unroll
  for (int i=0;i<128;i++) wr[i] = cwhhT[i*1024 + dir*512 + j];
  if (j<128) hbuf[j]=0.f;
  float cst = 0.f;
  __syncthreads();
  int tt0 = dir ? 255 : 0;
  float gnext = xg2[((size_t)dir*2048 + b*256 + tt0)*512 + j];
  for (int t=0;t<256;t++) {
    int tt = dir ? 255-t : t;
    float gsum = gnext;
    int tn = (t<255)? t+1 : 255;
    int ttn = dir ? 255-tn : tn;
    gnext = xg2[((size_t)dir*2048 + b*256 + ttn)*512 + j];
    #pragma unroll
    for (int i4=0;i4<32;i4++) {
      const float4 h4 = *(const float4*)&hbuf[4*i4];
      gsum += wr[4*i4]*h4.x + wr[4*i4+1]*h4.y + wr[4*i4+2]*h4.z + wr[4*i4+3]*h4.w;
    }
    gates[j] = gsum;
    __syncthreads();
    if (j<128) {
      float gi=gates[j], gf=gates[128+j], gc=gates[256+j], go=gates[384+j];
      cst = sigm(gf)*cst + sigm(gi)*tanhx(gc);
      float h = sigm(go)*tanhx(cst);
      hbuf[j]=h;
      lstm_out[((size_t)b*256+tt)*256 + dir*128 + j] = h;
    }
    __syncthreads();
  }
}

// ---------------- K6: wj = lstm_out . att_w ----------------
__global__ __launch_bounds__(256) void k_wj(
    const float* __restrict__ lstm_out, const float* __restrict__ att_w,
    float* __restrict__ wj)
{
  int w = threadIdx.x>>6, lane = threadIdx.x&63;
  int n = blockIdx.x*4 + w;
  const float4 a4 = *(const float4*)&att_w[lane*4];
  const float4 h4 = *(const float4*)&lstm_out[(size_t)n*256 + lane*4];
  float s = a4.x*h4.x + a4.y*h4.y + a4.z*h4.z + a4.w*h4.w;
  #pragma unroll
  for (int off=1; off<64; off<<=1) s += __shfl_xor(s, off);
  if (lane==0) wj[n] = s;
}

// ---------------- K7: Manhattan attention (8 query rows / block) ----------------
__global__ __launch_bounds__(256) void k_attention(
    const float* __restrict__ lstm_out, const float* __restrict__ wj,
    float* __restrict__ ctxbuf)
{
  __shared__ alignas(16) float hjt[64*260];
  __shared__ alignas(16) float hi8[8*260];
  __shared__ float sA[8*256];
  __shared__ alignas(16) float sT[256*8];
  int bid = blockIdx.x;
  int b = bid>>5, it0 = (bid&31)*8;
  int tid = threadIdx.x;
  for (int e=tid; e<8*64; e+=256) {
    int i = e>>6, dc = e&63;
    *(float4*)&hi8[i*260 + dc*4] = *(const float4*)&lstm_out[((size_t)b*256 + it0+i)*256 + dc*4];
  }
  int jl = tid>>2, ih = tid&3;
  for (int jt=0; jt<4; jt++) {
    __syncthreads();
    for (int e=tid; e<64*64; e+=256) {
      int r = e>>6, dc = e&63;
      *(float4*)&hjt[r*260 + dc*4] = *(const float4*)&lstm_out[((size_t)b*256 + jt*64+r)*256 + dc*4];
    }
    __syncthreads();
    int jg = jt*64 + jl;
    float wjv = wj[b*256 + jg];
    #pragma unroll
    for (int ii=0; ii<2; ii++) {
      int i = ih*2 + ii;
      float dist = 0.f;
      for (int dc=0; dc<64; dc++) {
        const float4 hj = *(const float4*)&hjt[jl*260 + dc*4];
        const float4 hv = *(const float4*)&hi8[i*260 + dc*4];
        dist += fabsf(hv.x-hj.x)+fabsf(hv.y-hj.y)+fabsf(hv.z-hj.z)+fabsf(hv.w-hj.w);
      }
      sA[i*256 + jg] = -wjv * dist;
    }
  }
  __syncthreads();
  {
    int i = tid>>5, l = tid&31;
    float m = -1e30f;
    float vals[8];
    #pragma unroll
    for (int q=0;q<8;q++) { vals[q] = sA[i*256 + l + q*32]; m = fmaxf(m, vals[q]); }
    #pragma unroll
    for (int off=1; off<32; off<<=1) m = fmaxf(m, __shfl_xor(m, off));
    float ssum = 0.f;
    #pragma unroll
    for (int q=0;q<8;q++) { vals[q] = __expf(vals[q]-m); ssum += vals[q]; }
    #pragma unroll
    for (int off=1; off<32; off<<=1) ssum += __shfl_xor(ssum, off);
    float inv = 1.f/ssum;
    #pragma unroll
    for (int q=0;q<8;q++) {
      int jg = l + q*32;
      float a = vals[q]*inv;
      sA[i*256+jg] = a;
      sT[jg*8 + i] = a;
    }
  }
  float acc[8];
  #pragma unroll
  for (int i=0;i<8;i++) acc[i]=0.f;
  int d = tid;
  for (int jt=0; jt<4; jt++) {
    __syncthreads();
    for (int e=tid; e<64*64; e+=256) {
      int r = e>>6, dc = e&63;
      *(float4*)&hjt[r*260 + dc*4] = *(const float4*)&lstm_out[((size_t)b*256 + jt*64+r)*256 + dc*4];
    }
    __syncthreads();
    for (int r=0;r<64;r++) {
      float v = hjt[r*260 + d];
      const float4 a0 = *(const float4*)&sT[(jt*64+r)*8];
      const float4 a1 = *(const float4*)&sT[(jt*64+r)*8+4];
      acc[0]+=a0.x*v; acc[1]+=a0.y*v; acc[2]+=a0.z*v; acc[3]+=a0.w*v;
      acc[4]+=a1.x*v; acc[5]+=a1.y*v; acc[6]+=a1.z*v; acc[7]+=a1.w*v;
    }
  }
  #pragma unroll
  for (int i=0;i<8;i++)
    ctxbuf[((size_t)b*256 + it0+i)*256 + d] = acc[i];
}

// ---------------- K8: projection + emissions (8 tokens / block) ----------------
__global__ __launch_bounds__(256) void k_proj_emit(
    const float* __restrict__ lstm_out, const float* __restrict__ ctxbuf,
    const float* __restrict__ pwT, const float* __restrict__ proj_b,
    const float* __restrict__ emit_w, const float* __restrict__ emit_b,
    float* __restrict__ em)
{
  __shared__ alignas(16) float attT[512*8];
  __shared__ alignas(16) float out8[8*260];
  int n0 = blockIdx.x*8, tid = threadIdx.x;
  for (int e=tid; e<4096; e+=256) {
    int d = e>>3, tok = e&7;
    int n = n0+tok;
    attT[e] = (d<256) ? lstm_out[(size_t)n*256 + d] : ctxbuf[(size_t)n*256 + d-256];
  }
  __syncthreads();
  int j = tid;
  {
    float acc[8];
    float bj = proj_b[j];
    #pragma unroll
    for (int t=0;t<8;t++) acc[t]=bj;
    for (int d=0; d<512; d++) {
      float w = pwT[d*256 + j];
      const float4 c0 = *(const float4*)&attT[d*8];
      const float4 c1 = *(const float4*)&attT[d*8+4];
      acc[0]+=w*c0.x; acc[1]+=w*c0.y; acc[2]+=w*c0.z; acc[3]+=w*c0.w;
      acc[4]+=w*c1.x; acc[5]+=w*c1.y; acc[6]+=w*c1.z; acc[7]+=w*c1.w;
    }
    #pragma unroll
    for (int t=0;t<8;t++) out8[t*260 + j] = acc[t];
  }
  __syncthreads();
  if (tid < 88) {
    int tok = tid/11, k = tid - tok*11;
    float acc = emit_b[k];
    for (int dc=0; dc<64; dc++) {
      const float4 o4 = *(const float4*)&out8[tok*260 + dc*4];
      const float4 w4 = *(const float4*)&emit_w[k*256 + dc*4];
      acc += o4.x*w4.x + o4.y*w4.y + o4.z*w4.z + o4.w*w4.w;
    }
    int n = n0+tok, bb = n>>8, tt = n&255;
    em[(tt*8+bb)*11 + k] = acc;
  }
}

// ---------------- K9: CRF NLL per batch (mask all-ones) ----------------
__global__ __launch_bounds__(64) void k_crf(
    const float* __restrict__ em, const int* __restrict__ tags,
    const float* __restrict__ trans, const float* __restrict__ cstart,
    const float* __restrict__ cend, float* __restrict__ nll)
{
  int b = blockIdx.x;
  int lane = threadIdx.x;
  // numerator (gold path)
  float np = 0.f;
  for (int t=1+lane; t<256; t+=64) {
    int tp = tags[b*256 + t-1], tc = tags[b*256 + t];
    np += trans[tp*11+tc] + em[(t*8+b)*11 + tc];
  }
  #pragma unroll
  for (int off=1; off<64; off<<=1) np += __shfl_xor(np, off);
  int t0 = tags[b*256], tl = tags[b*256+255];
  float num = cstart[t0] + em[b*11 + t0] + np + cend[tl];
  // forward algorithm; lane = kq*16 + kp ; lane kp holds alpha[kp] (replicated over kq)
  int kq = lane>>4, kp = lane&15;
  float t3[3];
  #pragma unroll
  for (int r=0;r<3;r++) {
    int k = kq*3+r;
    t3[r] = (k<11 && kp<11) ? trans[k*11+kp] : 0.f;
  }
  float alpha = (kp<11) ? cstart[kp] + em[b*11 + kp] : -1e30f;
  float ecur = (kp<11) ? em[(8+b)*11 + kp] : 0.f;
  for (int t=1; t<256; t++) {
    float enext = (t<255 && kp<11) ? em[((t+1)*8+b)*11 + kp] : 0.f;
    float a0 = __shfl(alpha, 0);
    float p = 0.f;
    #pragma unroll
    for (int r=0;r<3;r++) {
      int k = kq*3+r;
      if (k<11 && kp<11) {
        float ak = __shfl(alpha, k);
        p += __expf(ak + t3[r] - a0);
      }
    }
    p += __shfl_xor(p, 16);
    p += __shfl_xor(p, 32);
    alpha = (kp<11) ? a0 + __logf(p) + ecur : -1e30f;
    ecur = enext;
  }
  float val = (kq==0 && kp<11) ? alpha + cend[kp] : -1e30f;
  float m = val;
  #pragma unroll
  for (int off=1; off<64; off<<=1) m = fmaxf(m, __shfl_xor(m, off));
  float ex = (kq==0 && kp<11) ? __expf(val-m) : 0.f;
  #pragma unroll
  for (int off=1; off<64; off<<=1) ex += __shfl_xor(ex, off);
  if (lane==0) nll[b] = (m + __logf(ex)) - num;
}

// ---------------- K10: mean over batch -> d_out ----------------
__global__ __launch_bounds__(64) void k_final(const float* __restrict__ nll, float* __restrict__ out)
{
  int lane = threadIdx.x;
  float v = (lane<8) ? nll[lane] : 0.f;
  #pragma unroll
  for (int off=1; off<64; off<<=1) v += __shfl_xor(v, off);
  if (lane==0) out[0] = v * 0.125f;
}

// ---------------- launch ----------------
extern "C" void kernel_launch(void* const* d_in, const int* in_sizes, int n_in,
                              void* d_out, int out_size, void* d_ws, size_t ws_size,
                              hipStream_t stream)
{
  const int* word_ids = (const int*)d_in[0];
  const int* char_ids = (const int*)d_in[1];
  const int* tags     = (const int*)d_in[3];
  const float* wtab   = (const float*)d_in[4];
  const float* ctab   = (const float*)d_in[5];
  const float* w3 = (const float*)d_in[6];  const float* b3 = (const float*)d_in[7];
  const float* w5 = (const float*)d_in[8];  const float* b5 = (const float*)d_in[9];
  const float* w7 = (const float*)d_in[10]; const float* b7 = (const float*)d_in[11];
  const float* lctab  = (const float*)d_in[12];
  const float* lwih_f = (const float*)d_in[13];
  const float* lwhh_f = (const float*)d_in[14];
  const float* lb_f   = (const float*)d_in[15];
  const float* cwih_f = (const float*)d_in[16];
  const float* cwhh_f = (const float*)d_in[17];
  const float* cb_f   = (const float*)d_in[18];
  const float* lwih_b = (const float*)d_in[19];
  const float* lwhh_b = (const float*)d_in[20];
  const float* lb_b   = (const float*)d_in[21];
  const float* cwih_b = (const float*)d_in[22];
  const float* cwhh_b = (const float*)d_in[23];
  const float* cb_b   = (const float*)d_in[24];
  const float* fusion_w = (const float*)d_in[25];
  const float* fusion_b = (const float*)d_in[26];
  const float* att_w  = (const float*)d_in[27];
  const float* proj_w = (const float*)d_in[28];
  const float* proj_b = (const float*)d_in[29];
  const float* emit_w = (const float*)d_in[30];
  const float* emit_b = (const float*)d_in[31];
  const float* trans  = (const float*)d_in[32];
  const float* cstart = (const float*)d_in[33];
  const float* cend   = (const float*)d_in[34];

  float* ws = (float*)d_ws;
  float* cnn_feat  = ws + O_CNN;
  float* clstm_feat= ws + O_CLSTM;
  float* fused     = ws + O_FUSED;
  float* xg2       = ws + O_XG2;
  float* lstm_out  = ws + O_LSTM;
  float* wjv       = ws + O_WJ;
  float* ctxb      = ws + O_CTXB;
  float* emv       = ws + O_EM;
  float* nllv      = ws + O_NLL;
  float* fwT       = ws + O_FWT;
  float* cwihT     = ws + O_CWIHT;
  float* cwhhT     = ws + O_CWHHT;
  float* lwihT     = ws + O_LWIHT;
  float* lwhhT     = ws + O_LWHHT;
  float* pwT       = ws + O_PWT;

  k_transpose<<<2290,256,0,stream>>>(fusion_w, cwih_f, cwih_b, cwhh_f, cwhh_b,
                                     lwih_f, lwih_b, lwhh_f, lwhh_b, proj_w,
                                     fwT, cwihT, cwhhT, lwihT, lwhhT, pwT);
  k_charcnn<<<2048,384,0,stream>>>(char_ids, ctab, w3,b3,w5,b5,w7,b7, cnn_feat);
  k_charlstm<<<dim3(2048,2),256,0,stream>>>(char_ids, lctab, lwihT, lwhhT, lb_f, lb_b, clstm_feat);
  k_fusion<<<256,256,0,stream>>>(word_ids, wtab, cnn_feat, clstm_feat, fwT, fusion_b, fused);
  k_ctxxg<<<256,256,0,stream>>>(fused, cwihT, cb_f, cb_b, xg2);
  k_ctxlstm<<<16,512,0,stream>>>(xg2, cwhhT, lstm_out);
  k_wj<<<512,256,0,stream>>>(lstm_out, att_w, wjv);
  k_attention<<<256,256,0,stream>>>(lstm_out, wjv, ctxb);
  k_proj_emit<<<256,256,0,stream>>>(lstm_out, ctxb, pwT, proj_b, emit_w, emit_b, emv);
  k_crf<<<8,64,0,stream>>>(emv, tags, trans, cstart, cend, nllv);
  k_final<<<1,64,0,stream>>>(nllv, (float*)d_out);
}

// Round 2
// 1255.946 us; speedup vs baseline: 1.6025x; 1.6025x over previous
//
#include <hip/hip_runtime.h>
#include <math.h>

// ---------------- helpers ----------------
__device__ __forceinline__ float sigm(float x){ return 1.f/(1.f+__expf(-x)); }
__device__ __forceinline__ float tanhx(float x){
  x = fminf(fmaxf(x,-15.f),15.f);
  float e = __expf(2.f*x);
  return (e-1.f)/(e+1.f);
}

// ---------------- workspace layout (floats) ----------------
#define O_CNN    0            // 2048*96
#define O_CLSTM  196608       // 2048*100
#define O_FUSED  401408       // 2048*200
#define O_XG2    811008       // 2*2048*512
#define O_LSTM   2908160      // 2048*256
#define O_WJ     3432448      // 2048
#define O_CTXB   3434496      // 2048*256
#define O_EM     3958784      // 256*8*11
#define O_NLL    3981312      // 8
#define O_FWT    3981320      // 396*200
#define O_CWIHT  4060520      // 200*1024
#define O_CWHHT  4265320      // 128*1024
#define O_LWIHT  4396392      // 50*400
#define O_LWHHT  4416392      // 50*400
#define O_PWT    4436392      // 512*256
#define O_W3T    4567464      // 50*3*32 = 4800
#define O_W5T    4572264      // 50*5*32 = 8000
#define O_W7T    4580264      // 50*7*32 = 11200
#define WS_TOTAL 4591464

// ---------------- K0: transpose all weight matrices ----------------
__global__ __launch_bounds__(256) void k_transpose(
    const float* __restrict__ fusion_w,
    const float* __restrict__ cwih_f, const float* __restrict__ cwih_b,
    const float* __restrict__ cwhh_f, const float* __restrict__ cwhh_b,
    const float* __restrict__ lwih_f, const float* __restrict__ lwih_b,
    const float* __restrict__ lwhh_f, const float* __restrict__ lwhh_b,
    const float* __restrict__ proj_w,
    const float* __restrict__ w3, const float* __restrict__ w5, const float* __restrict__ w7,
    float* __restrict__ fwT, float* __restrict__ cwihT, float* __restrict__ cwhhT,
    float* __restrict__ lwihT, float* __restrict__ lwhhT, float* __restrict__ pwT,
    float* __restrict__ w3T, float* __restrict__ w5T, float* __restrict__ w7T)
{
  int id = blockIdx.x*256 + threadIdx.x;
  if (id < 79200) {                              // fusion_w [200,396] -> [396][200]
    int jr = id/396, d = id-jr*396;
    fwT[d*200 + jr] = fusion_w[id];
    return;
  }
  id -= 79200;
  if (id < 204800) {                             // ctx wih [512,200]x2 -> [200][1024]
    int dir = id/102400, e = id%102400;
    int r = e/200, d = e-r*200;
    cwihT[d*1024 + dir*512 + r] = (dir? cwih_b : cwih_f)[e];
    return;
  }
  id -= 204800;
  if (id < 131072) {                             // ctx whh [512,128]x2 -> [128][1024]
    int dir = id>>16, e = id&65535;
    int r = e>>7, d = e&127;
    cwhhT[d*1024 + dir*512 + r] = (dir? cwhh_b : cwhh_f)[e];
    return;
  }
  id -= 131072;
  if (id < 20000) {                              // clstm wih [200,50]x2 -> [50][400]
    int dir = id/10000, e = id%10000;
    int jr = e/50, i = e-jr*50;
    lwihT[i*400 + dir*200 + jr] = (dir? lwih_b : lwih_f)[e];
    return;
  }
  id -= 20000;
  if (id < 20000) {                              // clstm whh [200,50]x2 -> [50][400]
    int dir = id/10000, e = id%10000;
    int jr = e/50, i = e-jr*50;
    lwhhT[i*400 + dir*200 + jr] = (dir? lwhh_b : lwhh_f)[e];
    return;
  }
  id -= 20000;
  if (id < 131072) {                             // proj_w [256,512] -> [512][256]
    int jr = id>>9, d = id&511;
    pwT[d*256 + jr] = proj_w[id];
    return;
  }
  id -= 131072;
  if (id < 4800) {                               // w3 [32,50,3] -> [(i*3+t)*32+o]
    int o = id&31, q = id>>5, t = q%3, i = q/3;
    w3T[id] = w3[(o*50+i)*3 + t];
    return;
  }
  id -= 4800;
  if (id < 8000) {                               // w5 [32,50,5] -> [(i*5+t)*32+o]
    int o = id&31, q = id>>5, t = q%5, i = q/5;
    w5T[id] = w5[(o*50+i)*5 + t];
    return;
  }
  id -= 8000;
  if (id < 11200) {                              // w7 [32,50,7] -> [(i*7+t)*32+o]
    int o = id&31, q = id>>5, t = q%7, i = q/7;
    w7T[id] = w7[(o*50+i)*7 + t];
  }
}

// ---------------- K1: char CNN (per-token block), compile-time K ----------------
template<int K>
__device__ __forceinline__ void convk(
    const float* __restrict__ ce, const float* __restrict__ wT,
    const float* __restrict__ bb, float* __restrict__ outp, int o, int iq)
{
  constexpr int C = K/2;
  float acc[16];
  #pragma unroll
  for (int p=0;p<16;p++) acc[p]=0.f;
  int i0 = iq*13, i1 = (iq==3)? 50 : i0+13;
  for (int i=i0;i<i1;i++) {
    float col[16];
    #pragma unroll
    for (int t=0;t<16;t++) col[t] = ce[t*52+i];
    float wv[K];
    #pragma unroll
    for (int t=0;t<K;t++) wv[t] = wT[(i*K+t)*32 + o];
    #pragma unroll
    for (int t=0;t<K;t++) {
      #pragma unroll
      for (int p=0;p<16;p++) {
        constexpr int dummy = 0; (void)dummy;
        int pos = p + t - C;              // compile-time after unroll
        if (pos>=0 && pos<16) acc[p] += wv[t]*col[pos];
      }
    }
  }
  #pragma unroll
  for (int p=0;p<16;p++) { acc[p] += __shfl_xor(acc[p],1); acc[p] += __shfl_xor(acc[p],2); }
  if (iq==0) {
    float bias = bb[o];
    float m = 0.f;   // relu then max over positions = max(0, max_p y)
    #pragma unroll
    for (int p=0;p<16;p++) m = fmaxf(m, acc[p]+bias);
    *outp = m;
  }
}

__global__ __launch_bounds__(384) void k_charcnn(
    const int* __restrict__ char_ids, const float* __restrict__ ctab,
    const float* __restrict__ w3T, const float* __restrict__ b3,
    const float* __restrict__ w5T, const float* __restrict__ b5,
    const float* __restrict__ w7T, const float* __restrict__ b7,
    float* __restrict__ cnn_feat)
{
  __shared__ float ce[16*52];
  int n = blockIdx.x, tid = threadIdx.x;
  for (int e=tid; e<16*52; e+=384) {
    int t = e/52, i = e-52*t;
    ce[e] = (i<50) ? ctab[char_ids[n*16+t]*50 + i] : 0.f;
  }
  __syncthreads();
  int g = tid>>7, r = tid&127, o = r>>2, iq = r&3;   // g wave-uniform
  float* outp = &cnn_feat[n*96 + g*32 + o];
  if (g==0)      convk<3>(ce, w3T, b3, outp, o, iq);
  else if (g==1) convk<5>(ce, w5T, b5, outp, o, iq);
  else           convk<7>(ce, w7T, b7, outp, o, iq);
}

// ---------------- K2: char BiLSTM (per (token, dir) block), max over time ----------------
__global__ __launch_bounds__(256) void k_charlstm(
    const int* __restrict__ char_ids, const float* __restrict__ ctab,
    const float* __restrict__ lwihT, const float* __restrict__ lwhhT,
    const float* __restrict__ b_f, const float* __restrict__ b_b,
    float* __restrict__ clstm_feat)
{
  __shared__ alignas(16) float ce[16*52];
  __shared__ alignas(16) float hbuf[64];
  __shared__ float gates[200];
  int n = blockIdx.x, dir = blockIdx.y, tid = threadIdx.x;
  for (int e=tid; e<16*52; e+=256) {
    int t = e/52, i = e-52*t;
    int tt = dir ? 15-t : t;
    ce[e] = (i<50) ? ctab[char_ids[n*16+tt]*50 + i] : 0.f;
  }
  if (tid<64) hbuf[tid]=0.f;
  __syncthreads();
  int j = tid;
  float wr[52];
  float xg[16];
  if (j<200) {
    #pragma unroll
    for (int i=0;i<50;i++) wr[i] = lwihT[i*400 + dir*200 + j];
    wr[50]=0.f; wr[51]=0.f;
    float bj = (dir? b_b : b_f)[j];
    #pragma unroll
    for (int t=0;t<16;t++) xg[t]=bj;
    #pragma unroll
    for (int i4=0;i4<13;i4++) {
      float w0=wr[4*i4], w1=wr[4*i4+1], w2=wr[4*i4+2], w3v=wr[4*i4+3];
      #pragma unroll
      for (int t=0;t<16;t++) {
        const float4 c4 = *(const float4*)&ce[t*52 + 4*i4];
        xg[t] += w0*c4.x + w1*c4.y + w2*c4.z + w3v*c4.w;
      }
    }
    #pragma unroll
    for (int i=0;i<50;i++) wr[i] = lwhhT[i*400 + dir*200 + j];
  }
  float cst=0.f, m=-1e30f;
  __syncthreads();
  for (int t=0;t<16;t++) {
    if (j<200) {
      float gsum = xg[t];
      #pragma unroll
      for (int i4=0;i4<13;i4++) {
        const float4 h4 = *(const float4*)&hbuf[4*i4];
        gsum += wr[4*i4]*h4.x + wr[4*i4+1]*h4.y + wr[4*i4+2]*h4.z + wr[4*i4+3]*h4.w;
      }
      gates[j] = gsum;
    }
    __syncthreads();
    if (j<50) {
      float gi=gates[j], gf=gates[50+j], gc=gates[100+j], go=gates[150+j];
      cst = sigm(gf)*cst + sigm(gi)*tanhx(gc);
      float h = sigm(go)*tanhx(cst);
      m = fmaxf(m,h);
      hbuf[j]=h;
    }
    __syncthreads();
  }
  if (j<50) clstm_feat[n*100 + dir*50 + j] = m;
}

// ---------------- K3: fusion linear (8 tokens / block) ----------------
__global__ __launch_bounds__(256) void k_fusion(
    const int* __restrict__ word_ids, const float* __restrict__ wtab,
    const float* __restrict__ cnn_feat, const float* __restrict__ clstm_feat,
    const float* __restrict__ fwT, const float* __restrict__ fusion_b,
    float* __restrict__ fused)
{
  __shared__ alignas(16) float combT[400*8];
  int n0 = blockIdx.x*8, tid = threadIdx.x;
  for (int e=tid; e<3200; e+=256) {
    int d = e>>3, tok = e&7;
    int n = n0+tok;
    float v;
    if (d<200) v = wtab[word_ids[n]*200 + d];
    else if (d<296) v = cnn_feat[n*96 + d-200];
    else if (d<396) v = clstm_feat[n*100 + d-296];
    else v = 0.f;
    combT[e] = v;
  }
  __syncthreads();
  int j = tid;
  if (j<200) {
    float acc[8];
    float bj = fusion_b[j];
    #pragma unroll
    for (int t=0;t<8;t++) acc[t]=bj;
    for (int d=0; d<396; d++) {
      float w = fwT[d*200 + j];
      const float4 c0 = *(const float4*)&combT[d*8];
      const float4 c1 = *(const float4*)&combT[d*8+4];
      acc[0]+=w*c0.x; acc[1]+=w*c0.y; acc[2]+=w*c0.z; acc[3]+=w*c0.w;
      acc[4]+=w*c1.x; acc[5]+=w*c1.y; acc[6]+=w*c1.z; acc[7]+=w*c1.w;
    }
    #pragma unroll
    for (int t=0;t<8;t++) fused[(n0+t)*200 + j] = acc[t];
  }
}

// ---------------- K4: ctx LSTM input gates xg = fused @ WihT + b (both dirs) ----------------
__global__ __launch_bounds__(256) void k_ctxxg(
    const float* __restrict__ fused, const float* __restrict__ cwihT,
    const float* __restrict__ bf, const float* __restrict__ bbw,
    float* __restrict__ xg2)
{
  __shared__ alignas(16) float fuT[200*8];
  int n0 = blockIdx.x*8, tid = threadIdx.x;
  for (int e=tid; e<1600; e+=256) {
    int d = e>>3, tok = e&7;
    fuT[e] = fused[(n0+tok)*200 + d];
  }
  __syncthreads();
  int j = tid;
  float acc[4][8];
  #pragma unroll
  for (int s=0;s<4;s++) {
    int dir = s>>1, rr = (s&1)*256 + j;
    float bv = (dir? bbw : bf)[rr];
    #pragma unroll
    for (int t=0;t<8;t++) acc[s][t]=bv;
  }
  for (int d=0; d<200; d++) {
    float w0 = cwihT[d*1024 + j];
    float w1 = cwihT[d*1024 + 256 + j];
    float w2 = cwihT[d*1024 + 512 + j];
    float w3v= cwihT[d*1024 + 768 + j];
    const float4 f0 = *(const float4*)&fuT[d*8];
    const float4 f1 = *(const float4*)&fuT[d*8+4];
    float fv[8] = {f0.x,f0.y,f0.z,f0.w,f1.x,f1.y,f1.z,f1.w};
    #pragma unroll
    for (int t=0;t<8;t++) {
      acc[0][t]+=w0*fv[t]; acc[1][t]+=w1*fv[t]; acc[2][t]+=w2*fv[t]; acc[3][t]+=w3v*fv[t];
    }
  }
  #pragma unroll
  for (int s=0;s<4;s++) {
    int dir = s>>1, rr = (s&1)*256 + j;
    #pragma unroll
    for (int t=0;t<8;t++)
      xg2[((size_t)dir*2048 + n0+t)*512 + rr] = acc[s][t];
  }
}

// ---------------- K5: context BiLSTM recurrence (16 blocks: (b,dir)) ----------------
__global__ __launch_bounds__(512) void k_ctxlstm(
    const float* __restrict__ xg2, const float* __restrict__ cwhhT,
    float* __restrict__ lstm_out)
{
  __shared__ alignas(16) float hbuf[128];
  __shared__ float gates[512];
  int u = blockIdx.x;
  int b = u&7, dir = u>>3;
  int j = threadIdx.x;
  float wr[128];
  #pragma unroll
  for (int i=0;i<128;i++) wr[i] = cwhhT[i*1024 + dir*512 + j];
  if (j<128) hbuf[j]=0.f;
  float cst = 0.f;
  __syncthreads();
  int tt0 = dir ? 255 : 0;
  float gnext = xg2[((size_t)dir*2048 + b*256 + tt0)*512 + j];
  for (int t=0;t<256;t++) {
    int tt = dir ? 255-t : t;
    float gsum = gnext;
    int tn = (t<255)? t+1 : 255;
    int ttn = dir ? 255-tn : tn;
    gnext = xg2[((size_t)dir*2048 + b*256 + ttn)*512 + j];
    #pragma unroll
    for (int i4=0;i4<32;i4++) {
      const float4 h4 = *(const float4*)&hbuf[4*i4];
      gsum += wr[4*i4]*h4.x + wr[4*i4+1]*h4.y + wr[4*i4+2]*h4.z + wr[4*i4+3]*h4.w;
    }
    gates[j] = gsum;
    __syncthreads();
    if (j<128) {
      float gi=gates[j], gf=gates[128+j], gc=gates[256+j], go=gates[384+j];
      cst = sigm(gf)*cst + sigm(gi)*tanhx(gc);
      float h = sigm(go)*tanhx(cst);
      hbuf[j]=h;
      lstm_out[((size_t)b*256+tt)*256 + dir*128 + j] = h;
    }
    __syncthreads();
  }
}

// ---------------- K6: wj = lstm_out . att_w ----------------
__global__ __launch_bounds__(256) void k_wj(
    const float* __restrict__ lstm_out, const float* __restrict__ att_w,
    float* __restrict__ wj)
{
  int w = threadIdx.x>>6, lane = threadIdx.x&63;
  int n = blockIdx.x*4 + w;
  const float4 a4 = *(const float4*)&att_w[lane*4];
  const float4 h4 = *(const float4*)&lstm_out[(size_t)n*256 + lane*4];
  float s = a4.x*h4.x + a4.y*h4.y + a4.z*h4.z + a4.w*h4.w;
  #pragma unroll
  for (int off=1; off<64; off<<=1) s += __shfl_xor(s, off);
  if (lane==0) wj[n] = s;
}

// ---------------- K7: Manhattan attention (8 query rows / block) ----------------
__global__ __launch_bounds__(256) void k_attention(
    const float* __restrict__ lstm_out, const float* __restrict__ wj,
    float* __restrict__ ctxbuf)
{
  __shared__ alignas(16) float hjt[64*260];
  __shared__ alignas(16) float hi8[8*260];
  __shared__ float sA[8*256];
  __shared__ alignas(16) float sT[256*8];
  int bid = blockIdx.x;
  int b = bid>>5, it0 = (bid&31)*8;
  int tid = threadIdx.x;
  for (int e=tid; e<8*64; e+=256) {
    int i = e>>6, dc = e&63;
    *(float4*)&hi8[i*260 + dc*4] = *(const float4*)&lstm_out[((size_t)b*256 + it0+i)*256 + dc*4];
  }
  int jl = tid>>2, ih = tid&3;
  for (int jt=0; jt<4; jt++) {
    __syncthreads();
    for (int e=tid; e<64*64; e+=256) {
      int r = e>>6, dc = e&63;
      *(float4*)&hjt[r*260 + dc*4] = *(const float4*)&lstm_out[((size_t)b*256 + jt*64+r)*256 + dc*4];
    }
    __syncthreads();
    int jg = jt*64 + jl;
    float wjv = wj[b*256 + jg];
    #pragma unroll
    for (int ii=0; ii<2; ii++) {
      int i = ih*2 + ii;
      float dist = 0.f;
      for (int dc=0; dc<64; dc++) {
        const float4 hj = *(const float4*)&hjt[jl*260 + dc*4];
        const float4 hv = *(const float4*)&hi8[i*260 + dc*4];
        dist += fabsf(hv.x-hj.x)+fabsf(hv.y-hj.y)+fabsf(hv.z-hj.z)+fabsf(hv.w-hj.w);
      }
      sA[i*256 + jg] = -wjv * dist;
    }
  }
  __syncthreads();
  {
    int i = tid>>5, l = tid&31;
    float m = -1e30f;
    float vals[8];
    #pragma unroll
    for (int q=0;q<8;q++) { vals[q] = sA[i*256 + l + q*32]; m = fmaxf(m, vals[q]); }
    #pragma unroll
    for (int off=1; off<32; off<<=1) m = fmaxf(m, __shfl_xor(m, off));
    float ssum = 0.f;
    #pragma unroll
    for (int q=0;q<8;q++) { vals[q] = __expf(vals[q]-m); ssum += vals[q]; }
    #pragma unroll
    for (int off=1; off<32; off<<=1) ssum += __shfl_xor(ssum, off);
    float inv = 1.f/ssum;
    #pragma unroll
    for (int q=0;q<8;q++) {
      int jg = l + q*32;
      float a = vals[q]*inv;
      sA[i*256+jg] = a;
      sT[jg*8 + i] = a;
    }
  }
  float acc[8];
  #pragma unroll
  for (int i=0;i<8;i++) acc[i]=0.f;
  int d = tid;
  for (int jt=0; jt<4; jt++) {
    __syncthreads();
    for (int e=tid; e<64*64; e+=256) {
      int r = e>>6, dc = e&63;
      *(float4*)&hjt[r*260 + dc*4] = *(const float4*)&lstm_out[((size_t)b*256 + jt*64+r)*256 + dc*4];
    }
    __syncthreads();
    for (int r=0;r<64;r++) {
      float v = hjt[r*260 + d];
      const float4 a0 = *(const float4*)&sT[(jt*64+r)*8];
      const float4 a1 = *(const float4*)&sT[(jt*64+r)*8+4];
      acc[0]+=a0.x*v; acc[1]+=a0.y*v; acc[2]+=a0.z*v; acc[3]+=a0.w*v;
      acc[4]+=a1.x*v; acc[5]+=a1.y*v; acc[6]+=a1.z*v; acc[7]+=a1.w*v;
    }
  }
  #pragma unroll
  for (int i=0;i<8;i++)
    ctxbuf[((size_t)b*256 + it0+i)*256 + d] = acc[i];
}

// ---------------- K8: projection + emissions (8 tokens / block) ----------------
__global__ __launch_bounds__(256) void k_proj_emit(
    const float* __restrict__ lstm_out, const float* __restrict__ ctxbuf,
    const float* __restrict__ pwT, const float* __restrict__ proj_b,
    const float* __restrict__ emit_w, const float* __restrict__ emit_b,
    float* __restrict__ em)
{
  __shared__ alignas(16) float attT[512*8];
  __shared__ alignas(16) float out8[8*260];
  int n0 = blockIdx.x*8, tid = threadIdx.x;
  for (int e=tid; e<4096; e+=256) {
    int d = e>>3, tok = e&7;
    int n = n0+tok;
    attT[e] = (d<256) ? lstm_out[(size_t)n*256 + d] : ctxbuf[(size_t)n*256 + d-256];
  }
  __syncthreads();
  int j = tid;
  {
    float acc[8];
    float bj = proj_b[j];
    #pragma unroll
    for (int t=0;t<8;t++) acc[t]=bj;
    for (int d=0; d<512; d++) {
      float w = pwT[d*256 + j];
      const float4 c0 = *(const float4*)&attT[d*8];
      const float4 c1 = *(const float4*)&attT[d*8+4];
      acc[0]+=w*c0.x; acc[1]+=w*c0.y; acc[2]+=w*c0.z; acc[3]+=w*c0.w;
      acc[4]+=w*c1.x; acc[5]+=w*c1.y; acc[6]+=w*c1.z; acc[7]+=w*c1.w;
    }
    #pragma unroll
    for (int t=0;t<8;t++) out8[t*260 + j] = acc[t];
  }
  __syncthreads();
  if (tid < 88) {
    int tok = tid/11, k = tid - tok*11;
    float acc = emit_b[k];
    for (int dc=0; dc<64; dc++) {
      const float4 o4 = *(const float4*)&out8[tok*260 + dc*4];
      const float4 w4 = *(const float4*)&emit_w[k*256 + dc*4];
      acc += o4.x*w4.x + o4.y*w4.y + o4.z*w4.z + o4.w*w4.w;
    }
    int n = n0+tok, bb = n>>8, tt = n&255;
    em[(tt*8+bb)*11 + k] = acc;
  }
}

// ---------------- K9: CRF NLL per batch (mask all-ones) ----------------
__global__ __launch_bounds__(64) void k_crf(
    const float* __restrict__ em, const int* __restrict__ tags,
    const float* __restrict__ trans, const float* __restrict__ cstart,
    const float* __restrict__ cend, float* __restrict__ nll)
{
  int b = blockIdx.x;
  int lane = threadIdx.x;
  // numerator (gold path)
  float np = 0.f;
  for (int t=1+lane; t<256; t+=64) {
    int tp = tags[b*256 + t-1], tc = tags[b*256 + t];
    np += trans[tp*11+tc] + em[(t*8+b)*11 + tc];
  }
  #pragma unroll
  for (int off=1; off<64; off<<=1) np += __shfl_xor(np, off);
  int t0 = tags[b*256], tl = tags[b*256+255];
  float num = cstart[t0] + em[b*11 + t0] + np + cend[tl];
  // forward algorithm; lane = kq*16 + kp ; lane kp holds alpha[kp] (replicated over kq)
  int kq = lane>>4, kp = lane&15;
  float t3[3];
  #pragma unroll
  for (int r=0;r<3;r++) {
    int k = kq*3+r;
    t3[r] = (k<11 && kp<11) ? trans[k*11+kp] : 0.f;
  }
  float alpha = (kp<11) ? cstart[kp] + em[b*11 + kp] : -1e30f;
  float ecur = (kp<11) ? em[(8+b)*11 + kp] : 0.f;
  for (int t=1; t<256; t++) {
    float enext = (t<255 && kp<11) ? em[((t+1)*8+b)*11 + kp] : 0.f;
    float a0 = __shfl(alpha, 0);
    float p = 0.f;
    #pragma unroll
    for (int r=0;r<3;r++) {
      int k = kq*3+r;
      if (k<11 && kp<11) {
        float ak = __shfl(alpha, k);
        p += __expf(ak + t3[r] - a0);
      }
    }
    p += __shfl_xor(p, 16);
    p += __shfl_xor(p, 32);
    alpha = (kp<11) ? a0 + __logf(p) + ecur : -1e30f;
    ecur = enext;
  }
  float val = (kq==0 && kp<11) ? alpha + cend[kp] : -1e30f;
  float m = val;
  #pragma unroll
  for (int off=1; off<64; off<<=1) m = fmaxf(m, __shfl_xor(m, off));
  float ex = (kq==0 && kp<11) ? __expf(val-m) : 0.f;
  #pragma unroll
  for (int off=1; off<64; off<<=1) ex += __shfl_xor(ex, off);
  if (lane==0) nll[b] = (m + __logf(ex)) - num;
}

// ---------------- K10: mean over batch -> d_out ----------------
__global__ __launch_bounds__(64) void k_final(const float* __restrict__ nll, float* __restrict__ out)
{
  int lane = threadIdx.x;
  float v = (lane<8) ? nll[lane] : 0.f;
  #pragma unroll
  for (int off=1; off<64; off<<=1) v += __shfl_xor(v, off);
  if (lane==0) out[0] = v * 0.125f;
}

// ---------------- launch ----------------
extern "C" void kernel_launch(void* const* d_in, const int* in_sizes, int n_in,
                              void* d_out, int out_size, void* d_ws, size_t ws_size,
                              hipStream_t stream)
{
  const int* word_ids = (const int*)d_in[0];
  const int* char_ids = (const int*)d_in[1];
  const int* tags     = (const int*)d_in[3];
  const float* wtab   = (const float*)d_in[4];
  const float* ctab   = (const float*)d_in[5];
  const float* w3 = (const float*)d_in[6];  const float* b3 = (const float*)d_in[7];
  const float* w5 = (const float*)d_in[8];  const float* b5 = (const float*)d_in[9];
  const float* w7 = (const float*)d_in[10]; const float* b7 = (const float*)d_in[11];
  const float* lctab  = (const float*)d_in[12];
  const float* lwih_f = (const float*)d_in[13];
  const float* lwhh_f = (const float*)d_in[14];
  const float* lb_f   = (const float*)d_in[15];
  const float* cwih_f = (const float*)d_in[16];
  const float* cwhh_f = (const float*)d_in[17];
  const float* cb_f   = (const float*)d_in[18];
  const float* lwih_b = (const float*)d_in[19];
  const float* lwhh_b = (const float*)d_in[20];
  const float* lb_b   = (const float*)d_in[21];
  const float* cwih_b = (const float*)d_in[22];
  const float* cwhh_b = (const float*)d_in[23];
  const float* cb_b   = (const float*)d_in[24];
  const float* fusion_w = (const float*)d_in[25];
  const float* fusion_b = (const float*)d_in[26];
  const float* att_w  = (const float*)d_in[27];
  const float* proj_w = (const float*)d_in[28];
  const float* proj_b = (const float*)d_in[29];
  const float* emit_w = (const float*)d_in[30];
  const float* emit_b = (const float*)d_in[31];
  const float* trans  = (const float*)d_in[32];
  const float* cstart = (const float*)d_in[33];
  const float* cend   = (const float*)d_in[34];

  float* ws = (float*)d_ws;
  float* cnn_feat  = ws + O_CNN;
  float* clstm_feat= ws + O_CLSTM;
  float* fused     = ws + O_FUSED;
  float* xg2       = ws + O_XG2;
  float* lstm_out  = ws + O_LSTM;
  float* wjv       = ws + O_WJ;
  float* ctxb      = ws + O_CTXB;
  float* emv       = ws + O_EM;
  float* nllv      = ws + O_NLL;
  float* fwT       = ws + O_FWT;
  float* cwihT     = ws + O_CWIHT;
  float* cwhhT     = ws + O_CWHHT;
  float* lwihT     = ws + O_LWIHT;
  float* lwhhT     = ws + O_LWHHT;
  float* pwT       = ws + O_PWT;
  float* w3T       = ws + O_W3T;
  float* w5T       = ws + O_W5T;
  float* w7T       = ws + O_W7T;

  k_transpose<<<2384,256,0,stream>>>(fusion_w, cwih_f, cwih_b, cwhh_f, cwhh_b,
                                     lwih_f, lwih_b, lwhh_f, lwhh_b, proj_w,
                                     w3, w5, w7,
                                     fwT, cwihT, cwhhT, lwihT, lwhhT, pwT,
                                     w3T, w5T, w7T);
  k_charcnn<<<2048,384,0,stream>>>(char_ids, ctab, w3T,b3,w5T,b5,w7T,b7, cnn_feat);
  k_charlstm<<<dim3(2048,2),256,0,stream>>>(char_ids, lctab, lwihT, lwhhT, lb_f, lb_b, clstm_feat);
  k_fusion<<<256,256,0,stream>>>(word_ids, wtab, cnn_feat, clstm_feat, fwT, fusion_b, fused);
  k_ctxxg<<<256,256,0,stream>>>(fused, cwihT, cb_f, cb_b, xg2);
  k_ctxlstm<<<16,512,0,stream>>>(xg2, cwhhT, lstm_out);
  k_wj<<<512,256,0,stream>>>(lstm_out, att_w, wjv);
  k_attention<<<256,256,0,stream>>>(lstm_out, wjv, ctxb);
  k_proj_emit<<<256,256,0,stream>>>(lstm_out, ctxb, pwT, proj_b, emit_w, emit_b, emv);
  k_crf<<<8,64,0,stream>>>(emv, tags, trans, cstart, cend, nllv);
  k_final<<<1,64,0,stream>>>(nllv, (float*)d_out);
}

// Round 3
// 1028.719 us; speedup vs baseline: 1.9565x; 1.2209x over previous
//
#include <hip/hip_runtime.h>
#include <math.h>

// ---------------- helpers ----------------
__device__ __forceinline__ float sigm(float x){ return 1.f/(1.f+__expf(-x)); }
__device__ __forceinline__ float tanhx(float x){
  x = fminf(fmaxf(x,-15.f),15.f);
  float e = __expf(2.f*x);
  return (e-1.f)/(e+1.f);
}
__device__ __forceinline__ float rdlane(float v, int k){
  return __int_as_float(__builtin_amdgcn_readlane(__float_as_int(v), k));
}

// ---------------- workspace layout (floats) ----------------
#define O_CNN    0            // 2048*96
#define O_CLSTM  196608       // 2048*100
#define O_FUSED  401408       // 2048*200
#define O_XG2    811008       // 2*2048*512
#define O_LSTM   2908160      // 2048*256
#define O_WJ     3432448      // 2048
#define O_CTXB   3434496      // 2048*256
#define O_EM     3958784      // 256*8*11
#define O_NLL    3981312      // 8
#define O_FWT    3981320      // 396*200
#define O_CWIHT  4060520      // 200*1024
#define O_CWHHT  4265320      // 128*1024
#define O_LWIHT  4396392      // 50*400
#define O_LWHHT  4416392      // 50*400
#define O_PWT    4436392      // 512*256
#define O_W3T    4567464      // 50*3*32 = 4800
#define O_W5T    4572264      // 50*5*32 = 8000
#define O_W7T    4580264      // 50*7*32 = 11200
#define WS_TOTAL 4591464

// ---------------- K0: transpose all weight matrices ----------------
__global__ __launch_bounds__(256) void k_transpose(
    const float* __restrict__ fusion_w,
    const float* __restrict__ cwih_f, const float* __restrict__ cwih_b,
    const float* __restrict__ cwhh_f, const float* __restrict__ cwhh_b,
    const float* __restrict__ lwih_f, const float* __restrict__ lwih_b,
    const float* __restrict__ lwhh_f, const float* __restrict__ lwhh_b,
    const float* __restrict__ proj_w,
    const float* __restrict__ w3, const float* __restrict__ w5, const float* __restrict__ w7,
    float* __restrict__ fwT, float* __restrict__ cwihT, float* __restrict__ cwhhT,
    float* __restrict__ lwihT, float* __restrict__ lwhhT, float* __restrict__ pwT,
    float* __restrict__ w3T, float* __restrict__ w5T, float* __restrict__ w7T)
{
  int id = blockIdx.x*256 + threadIdx.x;
  if (id < 79200) {                              // fusion_w [200,396] -> [396][200]
    int jr = id/396, d = id-jr*396;
    fwT[d*200 + jr] = fusion_w[id];
    return;
  }
  id -= 79200;
  if (id < 204800) {                             // ctx wih [512,200]x2 -> [200][1024]
    int dir = id/102400, e = id%102400;
    int r = e/200, d = e-r*200;
    cwihT[d*1024 + dir*512 + r] = (dir? cwih_b : cwih_f)[e];
    return;
  }
  id -= 204800;
  if (id < 131072) {                             // ctx whh [512,128]x2 -> [128][1024]
    int dir = id>>16, e = id&65535;
    int r = e>>7, d = e&127;
    cwhhT[d*1024 + dir*512 + r] = (dir? cwhh_b : cwhh_f)[e];
    return;
  }
  id -= 131072;
  if (id < 20000) {                              // clstm wih [200,50]x2 -> [50][400]
    int dir = id/10000, e = id%10000;
    int jr = e/50, i = e-jr*50;
    lwihT[i*400 + dir*200 + jr] = (dir? lwih_b : lwih_f)[e];
    return;
  }
  id -= 20000;
  if (id < 20000) {                              // clstm whh [200,50]x2 -> [50][400]
    int dir = id/10000, e = id%10000;
    int jr = e/50, i = e-jr*50;
    lwhhT[i*400 + dir*200 + jr] = (dir? lwhh_b : lwhh_f)[e];
    return;
  }
  id -= 20000;
  if (id < 131072) {                             // proj_w [256,512] -> [512][256]
    int jr = id>>9, d = id&511;
    pwT[d*256 + jr] = proj_w[id];
    return;
  }
  id -= 131072;
  if (id < 4800) {                               // w3 [32,50,3] -> [(i*3+t)*32+o]
    int o = id&31, q = id>>5, t = q%3, i = q/3;
    w3T[id] = w3[(o*50+i)*3 + t];
    return;
  }
  id -= 4800;
  if (id < 8000) {                               // w5 [32,50,5] -> [(i*5+t)*32+o]
    int o = id&31, q = id>>5, t = q%5, i = q/5;
    w5T[id] = w5[(o*50+i)*5 + t];
    return;
  }
  id -= 8000;
  if (id < 11200) {                              // w7 [32,50,7] -> [(i*7+t)*32+o]
    int o = id&31, q = id>>5, t = q%7, i = q/7;
    w7T[id] = w7[(o*50+i)*7 + t];
  }
}

// ---------------- K1: char CNN (per-token block), compile-time K ----------------
template<int K>
__device__ __forceinline__ void convk(
    const float* __restrict__ ce, const float* __restrict__ wT,
    const float* __restrict__ bb, float* __restrict__ outp, int o, int iq)
{
  constexpr int C = K/2;
  float acc[16];
  #pragma unroll
  for (int p=0;p<16;p++) acc[p]=0.f;
  int i0 = iq*13, i1 = (iq==3)? 50 : i0+13;
  for (int i=i0;i<i1;i++) {
    float col[16];
    #pragma unroll
    for (int t=0;t<16;t++) col[t] = ce[t*52+i];
    float wv[K];
    #pragma unroll
    for (int t=0;t<K;t++) wv[t] = wT[(i*K+t)*32 + o];
    #pragma unroll
    for (int t=0;t<K;t++) {
      #pragma unroll
      for (int p=0;p<16;p++) {
        int pos = p + t - C;              // compile-time after unroll
        if (pos>=0 && pos<16) acc[p] += wv[t]*col[pos];
      }
    }
  }
  #pragma unroll
  for (int p=0;p<16;p++) { acc[p] += __shfl_xor(acc[p],1); acc[p] += __shfl_xor(acc[p],2); }
  if (iq==0) {
    float bias = bb[o];
    float m = 0.f;   // relu then max over positions = max(0, max_p y)
    #pragma unroll
    for (int p=0;p<16;p++) m = fmaxf(m, acc[p]+bias);
    *outp = m;
  }
}

__global__ __launch_bounds__(384) void k_charcnn(
    const int* __restrict__ char_ids, const float* __restrict__ ctab,
    const float* __restrict__ w3T, const float* __restrict__ b3,
    const float* __restrict__ w5T, const float* __restrict__ b5,
    const float* __restrict__ w7T, const float* __restrict__ b7,
    float* __restrict__ cnn_feat)
{
  __shared__ float ce[16*52];
  int n = blockIdx.x, tid = threadIdx.x;
  for (int e=tid; e<16*52; e+=384) {
    int t = e/52, i = e-52*t;
    ce[e] = (i<50) ? ctab[char_ids[n*16+t]*50 + i] : 0.f;
  }
  __syncthreads();
  int g = tid>>7, r = tid&127, o = r>>2, iq = r&3;   // g wave-uniform
  float* outp = &cnn_feat[n*96 + g*32 + o];
  if (g==0)      convk<3>(ce, w3T, b3, outp, o, iq);
  else if (g==1) convk<5>(ce, w5T, b5, outp, o, iq);
  else           convk<7>(ce, w7T, b7, outp, o, iq);
}

// ---------------- K2: char BiLSTM (per (token, dir) block), max over time ----------------
__global__ __launch_bounds__(256) void k_charlstm(
    const int* __restrict__ char_ids, const float* __restrict__ ctab,
    const float* __restrict__ lwihT, const float* __restrict__ lwhhT,
    const float* __restrict__ b_f, const float* __restrict__ b_b,
    float* __restrict__ clstm_feat)
{
  __shared__ alignas(16) float ce[16*52];
  __shared__ alignas(16) float hbuf[64];
  __shared__ float gates[200];
  int n = blockIdx.x, dir = blockIdx.y, tid = threadIdx.x;
  int l = tid&63;
  for (int e=tid; e<16*52; e+=256) {
    int t = e/52, i = e-52*t;
    int tt = dir ? 15-t : t;
    ce[e] = (i<50) ? ctab[char_ids[n*16+tt]*50 + i] : 0.f;
  }
  if (tid<64) hbuf[tid]=0.f;
  __syncthreads();
  int j = tid;
  float wr[50];
  float xg[16];
  if (j<200) {
    #pragma unroll
    for (int i=0;i<50;i++) wr[i] = lwihT[i*400 + dir*200 + j];
    float bj = (dir? b_b : b_f)[j];
    #pragma unroll
    for (int t=0;t<16;t++) xg[t]=bj;
    #pragma unroll
    for (int i=0;i<50;i++) {
      float w0=wr[i];
      #pragma unroll
      for (int t=0;t<16;t++) xg[t] += w0*ce[t*52 + i];
    }
    #pragma unroll
    for (int i=0;i<50;i++) wr[i] = lwhhT[i*400 + dir*200 + j];
  }
  float cst=0.f, m=-1e30f;
  __syncthreads();
  for (int t=0;t<16;t++) {
    float h0 = hbuf[l];                       // lanes hold h[l] (zeros beyond 50)
    if (j<200) {
      float gsum = xg[t];
      #pragma unroll
      for (int k=0;k<50;k++) gsum = fmaf(wr[k], rdlane(h0,k), gsum);
      gates[j] = gsum;
    }
    __syncthreads();
    if (j<50) {
      float gi=gates[j], gf=gates[50+j], gc=gates[100+j], go=gates[150+j];
      cst = sigm(gf)*cst + sigm(gi)*tanhx(gc);
      float h = sigm(go)*tanhx(cst);
      m = fmaxf(m,h);
      hbuf[j]=h;
    }
    __syncthreads();
  }
  if (j<50) clstm_feat[n*100 + dir*50 + j] = m;
}

// ---------------- K3: fusion linear (8 tokens / block) ----------------
__global__ __launch_bounds__(256) void k_fusion(
    const int* __restrict__ word_ids, const float* __restrict__ wtab,
    const float* __restrict__ cnn_feat, const float* __restrict__ clstm_feat,
    const float* __restrict__ fwT, const float* __restrict__ fusion_b,
    float* __restrict__ fused)
{
  __shared__ alignas(16) float combT[400*8];
  int n0 = blockIdx.x*8, tid = threadIdx.x;
  for (int e=tid; e<3200; e+=256) {
    int d = e>>3, tok = e&7;
    int n = n0+tok;
    float v;
    if (d<200) v = wtab[word_ids[n]*200 + d];
    else if (d<296) v = cnn_feat[n*96 + d-200];
    else if (d<396) v = clstm_feat[n*100 + d-296];
    else v = 0.f;
    combT[e] = v;
  }
  __syncthreads();
  int j = tid;
  if (j<200) {
    float acc[8];
    float bj = fusion_b[j];
    #pragma unroll
    for (int t=0;t<8;t++) acc[t]=bj;
    for (int d=0; d<396; d++) {
      float w = fwT[d*200 + j];
      const float4 c0 = *(const float4*)&combT[d*8];
      const float4 c1 = *(const float4*)&combT[d*8+4];
      acc[0]+=w*c0.x; acc[1]+=w*c0.y; acc[2]+=w*c0.z; acc[3]+=w*c0.w;
      acc[4]+=w*c1.x; acc[5]+=w*c1.y; acc[6]+=w*c1.z; acc[7]+=w*c1.w;
    }
    #pragma unroll
    for (int t=0;t<8;t++) fused[(n0+t)*200 + j] = acc[t];
  }
}

// ---------------- K4: ctx LSTM input gates xg = fused @ WihT + b (both dirs) ----------------
__global__ __launch_bounds__(256) void k_ctxxg(
    const float* __restrict__ fused, const float* __restrict__ cwihT,
    const float* __restrict__ bf, const float* __restrict__ bbw,
    float* __restrict__ xg2)
{
  __shared__ alignas(16) float fuT[200*8];
  int n0 = blockIdx.x*8, tid = threadIdx.x;
  for (int e=tid; e<1600; e+=256) {
    int d = e>>3, tok = e&7;
    fuT[e] = fused[(n0+tok)*200 + d];
  }
  __syncthreads();
  int j = tid;
  float acc[4][8];
  #pragma unroll
  for (int s=0;s<4;s++) {
    int dir = s>>1, rr = (s&1)*256 + j;
    float bv = (dir? bbw : bf)[rr];
    #pragma unroll
    for (int t=0;t<8;t++) acc[s][t]=bv;
  }
  for (int d=0; d<200; d++) {
    float w0 = cwihT[d*1024 + j];
    float w1 = cwihT[d*1024 + 256 + j];
    float w2 = cwihT[d*1024 + 512 + j];
    float w3v= cwihT[d*1024 + 768 + j];
    const float4 f0 = *(const float4*)&fuT[d*8];
    const float4 f1 = *(const float4*)&fuT[d*8+4];
    float fv[8] = {f0.x,f0.y,f0.z,f0.w,f1.x,f1.y,f1.z,f1.w};
    #pragma unroll
    for (int t=0;t<8;t++) {
      acc[0][t]+=w0*fv[t]; acc[1][t]+=w1*fv[t]; acc[2][t]+=w2*fv[t]; acc[3][t]+=w3v*fv[t];
    }
  }
  #pragma unroll
  for (int s=0;s<4;s++) {
    int dir = s>>1, rr = (s&1)*256 + j;
    #pragma unroll
    for (int t=0;t<8;t++)
      xg2[((size_t)dir*2048 + n0+t)*512 + rr] = acc[s][t];
  }
}

// ---------------- K5: context BiLSTM recurrence (16 blocks: (b,dir)) ----------------
// h-broadcast via readlane: 2 LDS reads/step instead of 32 ds_read_b128/thread.
__global__ __launch_bounds__(512,2) void k_ctxlstm(
    const float* __restrict__ xg2, const float* __restrict__ cwhhT,
    float* __restrict__ lstm_out)
{
  __shared__ float hbuf[128];
  __shared__ float gates[512];
  int u = blockIdx.x;
  int b = u&7, dir = u>>3;
  int j = threadIdx.x, l = j&63;
  float wr[128];
  #pragma unroll
  for (int i=0;i<128;i++) wr[i] = cwhhT[i*1024 + dir*512 + j];
  if (j<128) hbuf[j]=0.f;
  float cst = 0.f;
  __syncthreads();
  int tt0 = dir ? 255 : 0;
  float gnext = xg2[((size_t)dir*2048 + b*256 + tt0)*512 + j];
  for (int t=0;t<256;t++) {
    int tt = dir ? 255-t : t;
    float gsum = gnext;
    int tn = (t<255)? t+1 : 255;
    int ttn = dir ? 255-tn : tn;
    gnext = xg2[((size_t)dir*2048 + b*256 + ttn)*512 + j];
    float h0 = hbuf[l];
    float h1 = hbuf[64+l];
    #pragma unroll
    for (int k=0;k<64;k++) gsum = fmaf(wr[k],    rdlane(h0,k), gsum);
    #pragma unroll
    for (int k=0;k<64;k++) gsum = fmaf(wr[64+k], rdlane(h1,k), gsum);
    gates[j] = gsum;
    __syncthreads();
    if (j<128) {
      float gi=gates[j], gf=gates[128+j], gc=gates[256+j], go=gates[384+j];
      cst = sigm(gf)*cst + sigm(gi)*tanhx(gc);
      float h = sigm(go)*tanhx(cst);
      hbuf[j]=h;
      lstm_out[((size_t)b*256+tt)*256 + dir*128 + j] = h;
    }
    __syncthreads();
  }
}

// ---------------- K6: wj = lstm_out . att_w ----------------
__global__ __launch_bounds__(256) void k_wj(
    const float* __restrict__ lstm_out, const float* __restrict__ att_w,
    float* __restrict__ wj)
{
  int w = threadIdx.x>>6, lane = threadIdx.x&63;
  int n = blockIdx.x*4 + w;
  const float4 a4 = *(const float4*)&att_w[lane*4];
  const float4 h4 = *(const float4*)&lstm_out[(size_t)n*256 + lane*4];
  float s = a4.x*h4.x + a4.y*h4.y + a4.z*h4.z + a4.w*h4.w;
  #pragma unroll
  for (int off=1; off<64; off<<=1) s += __shfl_xor(s, off);
  if (lane==0) wj[n] = s;
}

// ---------------- K7: Manhattan attention, fused dist+softmax+ctx ----------------
// block = (b, 8-query tile); wave w handles queries i0=it0+2w, i1=i0+1.
// Phase 1 (dist): lanes cover j (float4), d staged in 32-row LDS chunks.
// Phase 2 (ctx):  lanes cover d (float4), j staged in 32-row LDS chunks.
// Per-thread state: 16 accumulators -> no spill possible.
__global__ __launch_bounds__(256,4) void k_attention(
    const float* __restrict__ lstm_out, const float* __restrict__ wj,
    float* __restrict__ ctxbuf)
{
  __shared__ alignas(16) float tile[32*260];   // 33.3 KB
  __shared__ float aT[8*256];                  // 8 KB alpha
  int b = blockIdx.y, it0 = blockIdx.x*8;
  int tid = threadIdx.x, w = tid>>6, l = tid&63;
  int i0 = it0 + 2*w, i1 = i0+1;
  const float* __restrict__ Lb = lstm_out + (size_t)b*256*256;

  // ---- phase 1: dist + softmax ----
  float d0x=0.f,d0y=0.f,d0z=0.f,d0w=0.f, d1x=0.f,d1y=0.f,d1z=0.f,d1w=0.f;
  for (int c=0;c<8;c++) {
    __syncthreads();
    #pragma unroll
    for (int k=0;k<8;k++) {                 // stage tile[dd][j] = Lb[j][c*32+dd]
      int idx = tid + k*256;
      int jj = idx>>3, kq = idx&7;
      const float4 v = *(const float4*)&Lb[jj*256 + c*32 + kq*4];
      tile[(kq*4+0)*260 + jj] = v.x;
      tile[(kq*4+1)*260 + jj] = v.y;
      tile[(kq*4+2)*260 + jj] = v.z;
      tile[(kq*4+3)*260 + jj] = v.w;
    }
    __syncthreads();
    #pragma unroll
    for (int dd=0;dd<32;dd++) {
      const float4 hj = *(const float4*)&tile[dd*260 + 4*l];
      float hi0 = tile[dd*260 + i0];
      float hi1 = tile[dd*260 + i1];
      d0x += fabsf(hj.x-hi0); d0y += fabsf(hj.y-hi0);
      d0z += fabsf(hj.z-hi0); d0w += fabsf(hj.w-hi0);
      d1x += fabsf(hj.x-hi1); d1y += fabsf(hj.y-hi1);
      d1z += fabsf(hj.z-hi1); d1w += fabsf(hj.w-hi1);
    }
  }
  const float4 wj4 = *(const float4*)&wj[b*256 + 4*l];
  float s0[4] = {-wj4.x*d0x, -wj4.y*d0y, -wj4.z*d0z, -wj4.w*d0w};
  float s1[4] = {-wj4.x*d1x, -wj4.y*d1y, -wj4.z*d1z, -wj4.w*d1w};
  // softmax over j (4 regs x 64 lanes) for i0 and i1
  float m0 = fmaxf(fmaxf(s0[0],s0[1]),fmaxf(s0[2],s0[3]));
  float m1 = fmaxf(fmaxf(s1[0],s1[1]),fmaxf(s1[2],s1[3]));
  #pragma unroll
  for (int off=1; off<64; off<<=1) {
    m0 = fmaxf(m0, __shfl_xor(m0, off));
    m1 = fmaxf(m1, __shfl_xor(m1, off));
  }
  float e0[4], e1[4]; float sum0=0.f, sum1=0.f;
  #pragma unroll
  for (int q=0;q<4;q++) {
    e0[q] = __expf(s0[q]-m0); sum0 += e0[q];
    e1[q] = __expf(s1[q]-m1); sum1 += e1[q];
  }
  #pragma unroll
  for (int off=1; off<64; off<<=1) {
    sum0 += __shfl_xor(sum0, off);
    sum1 += __shfl_xor(sum1, off);
  }
  float inv0 = 1.f/sum0, inv1 = 1.f/sum1;
  #pragma unroll
  for (int q=0;q<4;q++) {
    aT[(2*w  )*256 + 4*l + q] = e0[q]*inv0;
    aT[(2*w+1)*256 + 4*l + q] = e1[q]*inv1;
  }
  // (no barrier needed: each wave reads only the aT rows it wrote)

  // ---- phase 2: ctx = alpha @ H ----
  float a0x=0.f,a0y=0.f,a0z=0.f,a0w=0.f, a1x=0.f,a1y=0.f,a1z=0.f,a1w=0.f;
  for (int jc=0;jc<8;jc++) {
    __syncthreads();
    #pragma unroll
    for (int k=0;k<8;k++) {                 // stage tile[jl][d] = Lb[jc*32+jl][d]
      int idx = tid + k*256;
      int jl = idx>>6, q = idx&63;
      *(float4*)&tile[jl*260 + 4*q] = *(const float4*)&Lb[(jc*32+jl)*256 + 4*q];
    }
    __syncthreads();
    #pragma unroll
    for (int jl=0;jl<32;jl++) {
      const float4 h4 = *(const float4*)&tile[jl*260 + 4*l];
      float av0 = aT[(2*w  )*256 + jc*32 + jl];
      float av1 = aT[(2*w+1)*256 + jc*32 + jl];
      a0x += av0*h4.x; a0y += av0*h4.y; a0z += av0*h4.z; a0w += av0*h4.w;
      a1x += av1*h4.x; a1y += av1*h4.y; a1z += av1*h4.z; a1w += av1*h4.w;
    }
  }
  float4 o0 = {a0x,a0y,a0z,a0w};
  float4 o1 = {a1x,a1y,a1z,a1w};
  *(float4*)&ctxbuf[((size_t)b*256+i0)*256 + 4*l] = o0;
  *(float4*)&ctxbuf[((size_t)b*256+i1)*256 + 4*l] = o1;
}

// ---------------- K8: projection + emissions (8 tokens / block) ----------------
__global__ __launch_bounds__(256) void k_proj_emit(
    const float* __restrict__ lstm_out, const float* __restrict__ ctxbuf,
    const float* __restrict__ pwT, const float* __restrict__ proj_b,
    const float* __restrict__ emit_w, const float* __restrict__ emit_b,
    float* __restrict__ em)
{
  __shared__ alignas(16) float attT[512*8];
  __shared__ alignas(16) float out8[8*260];
  int n0 = blockIdx.x*8, tid = threadIdx.x;
  for (int e=tid; e<4096; e+=256) {
    int d = e>>3, tok = e&7;
    int n = n0+tok;
    attT[e] = (d<256) ? lstm_out[(size_t)n*256 + d] : ctxbuf[(size_t)n*256 + d-256];
  }
  __syncthreads();
  int j = tid;
  {
    float acc[8];
    float bj = proj_b[j];
    #pragma unroll
    for (int t=0;t<8;t++) acc[t]=bj;
    for (int d=0; d<512; d++) {
      float w = pwT[d*256 + j];
      const float4 c0 = *(const float4*)&attT[d*8];
      const float4 c1 = *(const float4*)&attT[d*8+4];
      acc[0]+=w*c0.x; acc[1]+=w*c0.y; acc[2]+=w*c0.z; acc[3]+=w*c0.w;
      acc[4]+=w*c1.x; acc[5]+=w*c1.y; acc[6]+=w*c1.z; acc[7]+=w*c1.w;
    }
    #pragma unroll
    for (int t=0;t<8;t++) out8[t*260 + j] = acc[t];
  }
  __syncthreads();
  if (tid < 88) {
    int tok = tid/11, k = tid - tok*11;
    float acc = emit_b[k];
    for (int dc=0; dc<64; dc++) {
      const float4 o4 = *(const float4*)&out8[tok*260 + dc*4];
      const float4 w4 = *(const float4*)&emit_w[k*256 + dc*4];
      acc += o4.x*w4.x + o4.y*w4.y + o4.z*w4.z + o4.w*w4.w;
    }
    int n = n0+tok, bb = n>>8, tt = n&255;
    em[(tt*8+bb)*11 + k] = acc;
  }
}

// ---------------- K9: CRF NLL per batch (mask all-ones) ----------------
__global__ __launch_bounds__(64) void k_crf(
    const float* __restrict__ em, const int* __restrict__ tags,
    const float* __restrict__ trans, const float* __restrict__ cstart,
    const float* __restrict__ cend, float* __restrict__ nll)
{
  int b = blockIdx.x;
  int lane = threadIdx.x;
  // numerator (gold path)
  float np = 0.f;
  for (int t=1+lane; t<256; t+=64) {
    int tp = tags[b*256 + t-1], tc = tags[b*256 + t];
    np += trans[tp*11+tc] + em[(t*8+b)*11 + tc];
  }
  #pragma unroll
  for (int off=1; off<64; off<<=1) np += __shfl_xor(np, off);
  int t0 = tags[b*256], tl = tags[b*256+255];
  float num = cstart[t0] + em[b*11 + t0] + np + cend[tl];
  // forward algorithm; lane = kq*16 + kp ; lane kp holds alpha[kp] (replicated over kq)
  int kq = lane>>4, kp = lane&15;
  float t3[3];
  #pragma unroll
  for (int r=0;r<3;r++) {
    int k = kq*3+r;
    t3[r] = (k<11 && kp<11) ? trans[k*11+kp] : 0.f;
  }
  float alpha = (kp<11) ? cstart[kp] + em[b*11 + kp] : -1e30f;
  float ecur = (kp<11) ? em[(8+b)*11 + kp] : 0.f;
  for (int t=1; t<256; t++) {
    float enext = (t<255 && kp<11) ? em[((t+1)*8+b)*11 + kp] : 0.f;
    float a0 = __shfl(alpha, 0);
    float p = 0.f;
    #pragma unroll
    for (int r=0;r<3;r++) {
      int k = kq*3+r;
      if (k<11 && kp<11) {
        float ak = __shfl(alpha, k);
        p += __expf(ak + t3[r] - a0);
      }
    }
    p += __shfl_xor(p, 16);
    p += __shfl_xor(p, 32);
    alpha = (kp<11) ? a0 + __logf(p) + ecur : -1e30f;
    ecur = enext;
  }
  float val = (kq==0 && kp<11) ? alpha + cend[kp] : -1e30f;
  float m = val;
  #pragma unroll
  for (int off=1; off<64; off<<=1) m = fmaxf(m, __shfl_xor(m, off));
  float ex = (kq==0 && kp<11) ? __expf(val-m) : 0.f;
  #pragma unroll
  for (int off=1; off<64; off<<=1) ex += __shfl_xor(ex, off);
  if (lane==0) nll[b] = (m + __logf(ex)) - num;
}

// ---------------- K10: mean over batch -> d_out ----------------
__global__ __launch_bounds__(64) void k_final(const float* __restrict__ nll, float* __restrict__ out)
{
  int lane = threadIdx.x;
  float v = (lane<8) ? nll[lane] : 0.f;
  #pragma unroll
  for (int off=1; off<64; off<<=1) v += __shfl_xor(v, off);
  if (lane==0) out[0] = v * 0.125f;
}

// ---------------- launch ----------------
extern "C" void kernel_launch(void* const* d_in, const int* in_sizes, int n_in,
                              void* d_out, int out_size, void* d_ws, size_t ws_size,
                              hipStream_t stream)
{
  const int* word_ids = (const int*)d_in[0];
  const int* char_ids = (const int*)d_in[1];
  const int* tags     = (const int*)d_in[3];
  const float* wtab   = (const float*)d_in[4];
  const float* ctab   = (const float*)d_in[5];
  const float* w3 = (const float*)d_in[6];  const float* b3 = (const float*)d_in[7];
  const float* w5 = (const float*)d_in[8];  const float* b5 = (const float*)d_in[9];
  const float* w7 = (const float*)d_in[10]; const float* b7 = (const float*)d_in[11];
  const float* lctab  = (const float*)d_in[12];
  const float* lwih_f = (const float*)d_in[13];
  const float* lwhh_f = (const float*)d_in[14];
  const float* lb_f   = (const float*)d_in[15];
  const float* cwih_f = (const float*)d_in[16];
  const float* cwhh_f = (const float*)d_in[17];
  const float* cb_f   = (const float*)d_in[18];
  const float* lwih_b = (const float*)d_in[19];
  const float* lwhh_b = (const float*)d_in[20];
  const float* lb_b   = (const float*)d_in[21];
  const float* cwih_b = (const float*)d_in[22];
  const float* cwhh_b = (const float*)d_in[23];
  const float* cb_b   = (const float*)d_in[24];
  const float* fusion_w = (const float*)d_in[25];
  const float* fusion_b = (const float*)d_in[26];
  const float* att_w  = (const float*)d_in[27];
  const float* proj_w = (const float*)d_in[28];
  const float* proj_b = (const float*)d_in[29];
  const float* emit_w = (const float*)d_in[30];
  const float* emit_b = (const float*)d_in[31];
  const float* trans  = (const float*)d_in[32];
  const float* cstart = (const float*)d_in[33];
  const float* cend   = (const float*)d_in[34];

  float* ws = (float*)d_ws;
  float* cnn_feat  = ws + O_CNN;
  float* clstm_feat= ws + O_CLSTM;
  float* fused     = ws + O_FUSED;
  float* xg2       = ws + O_XG2;
  float* lstm_out  = ws + O_LSTM;
  float* wjv       = ws + O_WJ;
  float* ctxb      = ws + O_CTXB;
  float* emv       = ws + O_EM;
  float* nllv      = ws + O_NLL;
  float* fwT       = ws + O_FWT;
  float* cwihT     = ws + O_CWIHT;
  float* cwhhT     = ws + O_CWHHT;
  float* lwihT     = ws + O_LWIHT;
  float* lwhhT     = ws + O_LWHHT;
  float* pwT       = ws + O_PWT;
  float* w3T       = ws + O_W3T;
  float* w5T       = ws + O_W5T;
  float* w7T       = ws + O_W7T;

  k_transpose<<<2384,256,0,stream>>>(fusion_w, cwih_f, cwih_b, cwhh_f, cwhh_b,
                                     lwih_f, lwih_b, lwhh_f, lwhh_b, proj_w,
                                     w3, w5, w7,
                                     fwT, cwihT, cwhhT, lwihT, lwhhT, pwT,
                                     w3T, w5T, w7T);
  k_charcnn<<<2048,384,0,stream>>>(char_ids, ctab, w3T,b3,w5T,b5,w7T,b7, cnn_feat);
  k_charlstm<<<dim3(2048,2),256,0,stream>>>(char_ids, lctab, lwihT, lwhhT, lb_f, lb_b, clstm_feat);
  k_fusion<<<256,256,0,stream>>>(word_ids, wtab, cnn_feat, clstm_feat, fwT, fusion_b, fused);
  k_ctxxg<<<256,256,0,stream>>>(fused, cwihT, cb_f, cb_b, xg2);
  k_ctxlstm<<<16,512,0,stream>>>(xg2, cwhhT, lstm_out);
  k_wj<<<512,256,0,stream>>>(lstm_out, att_w, wjv);
  k_attention<<<dim3(32,8),256,0,stream>>>(lstm_out, wjv, ctxb);
  k_proj_emit<<<256,256,0,stream>>>(lstm_out, ctxb, pwT, proj_b, emit_w, emit_b, emv);
  k_crf<<<8,64,0,stream>>>(emv, tags, trans, cstart, cend, nllv);
  k_final<<<1,64,0,stream>>>(nllv, (float*)d_out);
}

// Round 4
// 922.470 us; speedup vs baseline: 2.1818x; 1.1152x over previous
//
#include <hip/hip_runtime.h>
#include <math.h>

// ---------------- helpers ----------------
__device__ __forceinline__ float sigm(float x){ return 1.f/(1.f+__expf(-x)); }
__device__ __forceinline__ float tanhx(float x){
  x = fminf(fmaxf(x,-15.f),15.f);
  float e = __expf(2.f*x);
  return (e-1.f)/(e+1.f);
}
__device__ __forceinline__ float rdlane(float v, int k){
  return __int_as_float(__builtin_amdgcn_readlane(__float_as_int(v), k));
}

// ---------------- workspace layout (floats) ----------------
#define O_CNN    0            // 2048*96
#define O_CLSTM  196608       // 2048*100
#define O_FUSED  401408       // 2048*200
#define O_XG2    811008       // 2*2048*512
#define O_LSTM   2908160      // 2048*256
#define O_WJ     3432448      // 2048
#define O_CTXB   3434496      // 2048*256
#define O_EM     3958784      // 256*8*11
#define O_NLL    3981312      // 8
#define O_FWT    3981320      // 396*200
#define O_CWIHT  4060520      // 200*1024
#define O_CWHHT  4265320      // 128*1024
#define O_LWIHT  4396392      // 50*400
#define O_LWHHT  4416392      // 50*400
#define O_PWT    4436392      // 512*256
#define O_W3T    4567464      // 50*3*32 = 4800
#define O_W5T    4572264      // 50*5*32 = 8000
#define O_W7T    4580264      // 50*7*32 = 11200
#define WS_TOTAL 4591464

// ---------------- K0: transpose all weight matrices ----------------
__global__ __launch_bounds__(256) void k_transpose(
    const float* __restrict__ fusion_w,
    const float* __restrict__ cwih_f, const float* __restrict__ cwih_b,
    const float* __restrict__ cwhh_f, const float* __restrict__ cwhh_b,
    const float* __restrict__ lwih_f, const float* __restrict__ lwih_b,
    const float* __restrict__ lwhh_f, const float* __restrict__ lwhh_b,
    const float* __restrict__ proj_w,
    const float* __restrict__ w3, const float* __restrict__ w5, const float* __restrict__ w7,
    float* __restrict__ fwT, float* __restrict__ cwihT, float* __restrict__ cwhhT,
    float* __restrict__ lwihT, float* __restrict__ lwhhT, float* __restrict__ pwT,
    float* __restrict__ w3T, float* __restrict__ w5T, float* __restrict__ w7T)
{
  int id = blockIdx.x*256 + threadIdx.x;
  if (id < 79200) {                              // fusion_w [200,396] -> [396][200]
    int jr = id/396, d = id-jr*396;
    fwT[d*200 + jr] = fusion_w[id];
    return;
  }
  id -= 79200;
  if (id < 204800) {                             // ctx wih [512,200]x2 -> [200][1024]
    int dir = id/102400, e = id%102400;
    int r = e/200, d = e-r*200;
    cwihT[d*1024 + dir*512 + r] = (dir? cwih_b : cwih_f)[e];
    return;
  }
  id -= 204800;
  if (id < 131072) {                             // ctx whh [512,128]x2 -> [128][1024]
    int dir = id>>16, e = id&65535;
    int r = e>>7, d = e&127;
    cwhhT[d*1024 + dir*512 + r] = (dir? cwhh_b : cwhh_f)[e];
    return;
  }
  id -= 131072;
  if (id < 20000) {                              // clstm wih [200,50]x2 -> [50][400]
    int dir = id/10000, e = id%10000;
    int jr = e/50, i = e-jr*50;
    lwihT[i*400 + dir*200 + jr] = (dir? lwih_b : lwih_f)[e];
    return;
  }
  id -= 20000;
  if (id < 20000) {                              // clstm whh [200,50]x2 -> [50][400]
    int dir = id/10000, e = id%10000;
    int jr = e/50, i = e-jr*50;
    lwhhT[i*400 + dir*200 + jr] = (dir? lwhh_b : lwhh_f)[e];
    return;
  }
  id -= 20000;
  if (id < 131072) {                             // proj_w [256,512] -> [512][256]
    int jr = id>>9, d = id&511;
    pwT[d*256 + jr] = proj_w[id];
    return;
  }
  id -= 131072;
  if (id < 4800) {                               // w3 [32,50,3] -> [(i*3+t)*32+o]
    int o = id&31, q = id>>5, t = q%3, i = q/3;
    w3T[id] = w3[(o*50+i)*3 + t];
    return;
  }
  id -= 4800;
  if (id < 8000) {                               // w5 [32,50,5] -> [(i*5+t)*32+o]
    int o = id&31, q = id>>5, t = q%5, i = q/5;
    w5T[id] = w5[(o*50+i)*5 + t];
    return;
  }
  id -= 8000;
  if (id < 11200) {                              // w7 [32,50,7] -> [(i*7+t)*32+o]
    int o = id&31, q = id>>5, t = q%7, i = q/7;
    w7T[id] = w7[(o*50+i)*7 + t];
  }
}

// ---------------- K1: char CNN (per-token block), compile-time K ----------------
template<int K>
__device__ __forceinline__ void convk(
    const float* __restrict__ ce, const float* __restrict__ wT,
    const float* __restrict__ bb, float* __restrict__ outp, int o, int iq)
{
  constexpr int C = K/2;
  float acc[16];
  #pragma unroll
  for (int p=0;p<16;p++) acc[p]=0.f;
  int i0 = iq*13, i1 = (iq==3)? 50 : i0+13;
  for (int i=i0;i<i1;i++) {
    float col[16];
    #pragma unroll
    for (int t=0;t<16;t++) col[t] = ce[t*52+i];
    float wv[K];
    #pragma unroll
    for (int t=0;t<K;t++) wv[t] = wT[(i*K+t)*32 + o];
    #pragma unroll
    for (int t=0;t<K;t++) {
      #pragma unroll
      for (int p=0;p<16;p++) {
        int pos = p + t - C;              // compile-time after unroll
        if (pos>=0 && pos<16) acc[p] += wv[t]*col[pos];
      }
    }
  }
  #pragma unroll
  for (int p=0;p<16;p++) { acc[p] += __shfl_xor(acc[p],1); acc[p] += __shfl_xor(acc[p],2); }
  if (iq==0) {
    float bias = bb[o];
    float m = 0.f;   // relu then max over positions = max(0, max_p y)
    #pragma unroll
    for (int p=0;p<16;p++) m = fmaxf(m, acc[p]+bias);
    *outp = m;
  }
}

__global__ __launch_bounds__(384) void k_charcnn(
    const int* __restrict__ char_ids, const float* __restrict__ ctab,
    const float* __restrict__ w3T, const float* __restrict__ b3,
    const float* __restrict__ w5T, const float* __restrict__ b5,
    const float* __restrict__ w7T, const float* __restrict__ b7,
    float* __restrict__ cnn_feat)
{
  __shared__ float ce[16*52];
  int n = blockIdx.x, tid = threadIdx.x;
  for (int e=tid; e<16*52; e+=384) {
    int t = e/52, i = e-52*t;
    ce[e] = (i<50) ? ctab[char_ids[n*16+t]*50 + i] : 0.f;
  }
  __syncthreads();
  int g = tid>>7, r = tid&127, o = r>>2, iq = r&3;   // g wave-uniform
  float* outp = &cnn_feat[n*96 + g*32 + o];
  if (g==0)      convk<3>(ce, w3T, b3, outp, o, iq);
  else if (g==1) convk<5>(ce, w5T, b5, outp, o, iq);
  else           convk<7>(ce, w7T, b7, outp, o, iq);
}

// ---------------- K2: char BiLSTM (per (token, dir) block), max over time ----------------
__global__ __launch_bounds__(256) void k_charlstm(
    const int* __restrict__ char_ids, const float* __restrict__ ctab,
    const float* __restrict__ lwihT, const float* __restrict__ lwhhT,
    const float* __restrict__ b_f, const float* __restrict__ b_b,
    float* __restrict__ clstm_feat)
{
  __shared__ alignas(16) float ce[16*52];
  __shared__ alignas(16) float hbuf[64];
  __shared__ float gates[200];
  int n = blockIdx.x, dir = blockIdx.y, tid = threadIdx.x;
  int l = tid&63;
  for (int e=tid; e<16*52; e+=256) {
    int t = e/52, i = e-52*t;
    int tt = dir ? 15-t : t;
    ce[e] = (i<50) ? ctab[char_ids[n*16+tt]*50 + i] : 0.f;
  }
  if (tid<64) hbuf[tid]=0.f;
  __syncthreads();
  int j = tid;
  float wr[50];
  float xg[16];
  if (j<200) {
    #pragma unroll
    for (int i=0;i<50;i++) wr[i] = lwihT[i*400 + dir*200 + j];
    float bj = (dir? b_b : b_f)[j];
    #pragma unroll
    for (int t=0;t<16;t++) xg[t]=bj;
    #pragma unroll
    for (int i=0;i<50;i++) {
      float w0=wr[i];
      #pragma unroll
      for (int t=0;t<16;t++) xg[t] += w0*ce[t*52 + i];
    }
    #pragma unroll
    for (int i=0;i<50;i++) wr[i] = lwhhT[i*400 + dir*200 + j];
    #pragma unroll
    for (int i=0;i<50;i++) asm volatile("" : "+v"(wr[i]));   // pin Whh row in VGPRs
  }
  float cst=0.f, m=-1e30f;
  __syncthreads();
  for (int t=0;t<16;t++) {
    float h0 = hbuf[l];                       // lanes hold h[l] (zeros beyond 50)
    if (j<200) {
      float g0=0.f, g1=0.f, g2=0.f, g3=0.f;
      #pragma unroll
      for (int k=0;k<48;k+=4) {
        g0 = fmaf(wr[k+0], rdlane(h0,k+0), g0);
        g1 = fmaf(wr[k+1], rdlane(h0,k+1), g1);
        g2 = fmaf(wr[k+2], rdlane(h0,k+2), g2);
        g3 = fmaf(wr[k+3], rdlane(h0,k+3), g3);
      }
      g0 = fmaf(wr[48], rdlane(h0,48), g0);
      g1 = fmaf(wr[49], rdlane(h0,49), g1);
      gates[j] = xg[t] + ((g0+g1)+(g2+g3));
    }
    __syncthreads();
    if (j<50) {
      float gi=gates[j], gf=gates[50+j], gc=gates[100+j], go=gates[150+j];
      cst = sigm(gf)*cst + sigm(gi)*tanhx(gc);
      float h = sigm(go)*tanhx(cst);
      m = fmaxf(m,h);
      hbuf[j]=h;
    }
    __syncthreads();
  }
  if (j<50) clstm_feat[n*100 + dir*50 + j] = m;
}

// ---------------- K3: fusion linear (8 tokens / block) ----------------
__global__ __launch_bounds__(256) void k_fusion(
    const int* __restrict__ word_ids, const float* __restrict__ wtab,
    const float* __restrict__ cnn_feat, const float* __restrict__ clstm_feat,
    const float* __restrict__ fwT, const float* __restrict__ fusion_b,
    float* __restrict__ fused)
{
  __shared__ alignas(16) float combT[400*8];
  int n0 = blockIdx.x*8, tid = threadIdx.x;
  for (int e=tid; e<3200; e+=256) {
    int d = e>>3, tok = e&7;
    int n = n0+tok;
    float v;
    if (d<200) v = wtab[word_ids[n]*200 + d];
    else if (d<296) v = cnn_feat[n*96 + d-200];
    else if (d<396) v = clstm_feat[n*100 + d-296];
    else v = 0.f;
    combT[e] = v;
  }
  __syncthreads();
  int j = tid;
  if (j<200) {
    float acc[8];
    float bj = fusion_b[j];
    #pragma unroll
    for (int t=0;t<8;t++) acc[t]=bj;
    for (int d=0; d<396; d++) {
      float w = fwT[d*200 + j];
      const float4 c0 = *(const float4*)&combT[d*8];
      const float4 c1 = *(const float4*)&combT[d*8+4];
      acc[0]+=w*c0.x; acc[1]+=w*c0.y; acc[2]+=w*c0.z; acc[3]+=w*c0.w;
      acc[4]+=w*c1.x; acc[5]+=w*c1.y; acc[6]+=w*c1.z; acc[7]+=w*c1.w;
    }
    #pragma unroll
    for (int t=0;t<8;t++) fused[(n0+t)*200 + j] = acc[t];
  }
}

// ---------------- K4: ctx LSTM input gates xg = fused @ WihT + b (both dirs) ----------------
__global__ __launch_bounds__(256) void k_ctxxg(
    const float* __restrict__ fused, const float* __restrict__ cwihT,
    const float* __restrict__ bf, const float* __restrict__ bbw,
    float* __restrict__ xg2)
{
  __shared__ alignas(16) float fuT[200*8];
  int n0 = blockIdx.x*8, tid = threadIdx.x;
  for (int e=tid; e<1600; e+=256) {
    int d = e>>3, tok = e&7;
    fuT[e] = fused[(n0+tok)*200 + d];
  }
  __syncthreads();
  int j = tid;
  float acc[4][8];
  #pragma unroll
  for (int s=0;s<4;s++) {
    int dir = s>>1, rr = (s&1)*256 + j;
    float bv = (dir? bbw : bf)[rr];
    #pragma unroll
    for (int t=0;t<8;t++) acc[s][t]=bv;
  }
  for (int d=0; d<200; d++) {
    float w0 = cwihT[d*1024 + j];
    float w1 = cwihT[d*1024 + 256 + j];
    float w2 = cwihT[d*1024 + 512 + j];
    float w3v= cwihT[d*1024 + 768 + j];
    const float4 f0 = *(const float4*)&fuT[d*8];
    const float4 f1 = *(const float4*)&fuT[d*8+4];
    float fv[8] = {f0.x,f0.y,f0.z,f0.w,f1.x,f1.y,f1.z,f1.w};
    #pragma unroll
    for (int t=0;t<8;t++) {
      acc[0][t]+=w0*fv[t]; acc[1][t]+=w1*fv[t]; acc[2][t]+=w2*fv[t]; acc[3][t]+=w3v*fv[t];
    }
  }
  #pragma unroll
  for (int s=0;s<4;s++) {
    int dir = s>>1, rr = (s&1)*256 + j;
    #pragma unroll
    for (int t=0;t<8;t++)
      xg2[((size_t)dir*2048 + n0+t)*512 + rr] = acc[s][t];
  }
}

// ---------------- K5: context BiLSTM recurrence (16 blocks: (b,dir)) ----------------
// Whh row pinned in VGPRs (asm) -- R3 showed the compiler rematerialized the
// cwhhT loads inside the t-loop (VGPR_Count=76 < 128), re-reading 256KB/step
// from L2. 4 independent accumulators break the serial FMA chain.
__global__ __launch_bounds__(512,2) void k_ctxlstm(
    const float* __restrict__ xg2, const float* __restrict__ cwhhT,
    float* __restrict__ lstm_out)
{
  __shared__ float hbuf[128];
  __shared__ float gates[512];
  int u = blockIdx.x;
  int b = u&7, dir = u>>3;
  int j = threadIdx.x, l = j&63;
  float wr[128];
  #pragma unroll
  for (int i=0;i<128;i++) wr[i] = cwhhT[i*1024 + dir*512 + j];
  #pragma unroll
  for (int i=0;i<128;i++) asm volatile("" : "+v"(wr[i]));   // pin in VGPRs
  if (j<128) hbuf[j]=0.f;
  float cst = 0.f;
  __syncthreads();
  int tt0 = dir ? 255 : 0;
  float gnext = xg2[((size_t)dir*2048 + b*256 + tt0)*512 + j];
  for (int t=0;t<256;t++) {
    int tt = dir ? 255-t : t;
    float xgv = gnext;
    int tn = (t<255)? t+1 : 255;
    int ttn = dir ? 255-tn : tn;
    gnext = xg2[((size_t)dir*2048 + b*256 + ttn)*512 + j];
    float h0 = hbuf[l];
    float h1 = hbuf[64+l];
    float g0=0.f, g1=0.f, g2=0.f, g3=0.f;
    #pragma unroll
    for (int k=0;k<64;k+=4) {
      g0 = fmaf(wr[k+0], rdlane(h0,k+0), g0);
      g1 = fmaf(wr[k+1], rdlane(h0,k+1), g1);
      g2 = fmaf(wr[k+2], rdlane(h0,k+2), g2);
      g3 = fmaf(wr[k+3], rdlane(h0,k+3), g3);
    }
    #pragma unroll
    for (int k=0;k<64;k+=4) {
      g0 = fmaf(wr[64+k+0], rdlane(h1,k+0), g0);
      g1 = fmaf(wr[64+k+1], rdlane(h1,k+1), g1);
      g2 = fmaf(wr[64+k+2], rdlane(h1,k+2), g2);
      g3 = fmaf(wr[64+k+3], rdlane(h1,k+3), g3);
    }
    gates[j] = xgv + ((g0+g1)+(g2+g3));
    __syncthreads();
    if (j<128) {
      float gi=gates[j], gf=gates[128+j], gc=gates[256+j], go=gates[384+j];
      cst = sigm(gf)*cst + sigm(gi)*tanhx(gc);
      float h = sigm(go)*tanhx(cst);
      hbuf[j]=h;
      lstm_out[((size_t)b*256+tt)*256 + dir*128 + j] = h;
    }
    __syncthreads();
  }
}

// ---------------- K6: wj = lstm_out . att_w ----------------
__global__ __launch_bounds__(256) void k_wj(
    const float* __restrict__ lstm_out, const float* __restrict__ att_w,
    float* __restrict__ wj)
{
  int w = threadIdx.x>>6, lane = threadIdx.x&63;
  int n = blockIdx.x*4 + w;
  const float4 a4 = *(const float4*)&att_w[lane*4];
  const float4 h4 = *(const float4*)&lstm_out[(size_t)n*256 + lane*4];
  float s = a4.x*h4.x + a4.y*h4.y + a4.z*h4.z + a4.w*h4.w;
  #pragma unroll
  for (int off=1; off<64; off<<=1) s += __shfl_xor(s, off);
  if (lane==0) wj[n] = s;
}

// ---------------- K7: Manhattan attention, fused dist+softmax+ctx ----------------
__global__ __launch_bounds__(256,4) void k_attention(
    const float* __restrict__ lstm_out, const float* __restrict__ wj,
    float* __restrict__ ctxbuf)
{
  __shared__ alignas(16) float tile[32*260];   // 33.3 KB
  __shared__ float aT[8*256];                  // 8 KB alpha
  int b = blockIdx.y, it0 = blockIdx.x*8;
  int tid = threadIdx.x, w = tid>>6, l = tid&63;
  int i0 = it0 + 2*w, i1 = i0+1;
  const float* __restrict__ Lb = lstm_out + (size_t)b*256*256;

  // ---- phase 1: dist + softmax ----
  float d0x=0.f,d0y=0.f,d0z=0.f,d0w=0.f, d1x=0.f,d1y=0.f,d1z=0.f,d1w=0.f;
  for (int c=0;c<8;c++) {
    __syncthreads();
    #pragma unroll
    for (int k=0;k<8;k++) {                 // stage tile[dd][j] = Lb[j][c*32+dd]
      int idx = tid + k*256;
      int jj = idx>>3, kq = idx&7;
      const float4 v = *(const float4*)&Lb[jj*256 + c*32 + kq*4];
      tile[(kq*4+0)*260 + jj] = v.x;
      tile[(kq*4+1)*260 + jj] = v.y;
      tile[(kq*4+2)*260 + jj] = v.z;
      tile[(kq*4+3)*260 + jj] = v.w;
    }
    __syncthreads();
    #pragma unroll
    for (int dd=0;dd<32;dd++) {
      const float4 hj = *(const float4*)&tile[dd*260 + 4*l];
      float hi0 = tile[dd*260 + i0];
      float hi1 = tile[dd*260 + i1];
      d0x += fabsf(hj.x-hi0); d0y += fabsf(hj.y-hi0);
      d0z += fabsf(hj.z-hi0); d0w += fabsf(hj.w-hi0);
      d1x += fabsf(hj.x-hi1); d1y += fabsf(hj.y-hi1);
      d1z += fabsf(hj.z-hi1); d1w += fabsf(hj.w-hi1);
    }
  }
  const float4 wj4 = *(const float4*)&wj[b*256 + 4*l];
  float s0[4] = {-wj4.x*d0x, -wj4.y*d0y, -wj4.z*d0z, -wj4.w*d0w};
  float s1[4] = {-wj4.x*d1x, -wj4.y*d1y, -wj4.z*d1z, -wj4.w*d1w};
  float m0 = fmaxf(fmaxf(s0[0],s0[1]),fmaxf(s0[2],s0[3]));
  float m1 = fmaxf(fmaxf(s1[0],s1[1]),fmaxf(s1[2],s1[3]));
  #pragma unroll
  for (int off=1; off<64; off<<=1) {
    m0 = fmaxf(m0, __shfl_xor(m0, off));
    m1 = fmaxf(m1, __shfl_xor(m1, off));
  }
  float e0[4], e1[4]; float sum0=0.f, sum1=0.f;
  #pragma unroll
  for (int q=0;q<4;q++) {
    e0[q] = __expf(s0[q]-m0); sum0 += e0[q];
    e1[q] = __expf(s1[q]-m1); sum1 += e1[q];
  }
  #pragma unroll
  for (int off=1; off<64; off<<=1) {
    sum0 += __shfl_xor(sum0, off);
    sum1 += __shfl_xor(sum1, off);
  }
  float inv0 = 1.f/sum0, inv1 = 1.f/sum1;
  #pragma unroll
  for (int q=0;q<4;q++) {
    aT[(2*w  )*256 + 4*l + q] = e0[q]*inv0;
    aT[(2*w+1)*256 + 4*l + q] = e1[q]*inv1;
  }

  // ---- phase 2: ctx = alpha @ H ----
  float a0x=0.f,a0y=0.f,a0z=0.f,a0w=0.f, a1x=0.f,a1y=0.f,a1z=0.f,a1w=0.f;
  for (int jc=0;jc<8;jc++) {
    __syncthreads();
    #pragma unroll
    for (int k=0;k<8;k++) {                 // stage tile[jl][d] = Lb[jc*32+jl][d]
      int idx = tid + k*256;
      int jl = idx>>6, q = idx&63;
      *(float4*)&tile[jl*260 + 4*q] = *(const float4*)&Lb[(jc*32+jl)*256 + 4*q];
    }
    __syncthreads();
    #pragma unroll
    for (int jl=0;jl<32;jl++) {
      const float4 h4 = *(const float4*)&tile[jl*260 + 4*l];
      float av0 = aT[(2*w  )*256 + jc*32 + jl];
      float av1 = aT[(2*w+1)*256 + jc*32 + jl];
      a0x += av0*h4.x; a0y += av0*h4.y; a0z += av0*h4.z; a0w += av0*h4.w;
      a1x += av1*h4.x; a1y += av1*h4.y; a1z += av1*h4.z; a1w += av1*h4.w;
    }
  }
  float4 o0 = {a0x,a0y,a0z,a0w};
  float4 o1 = {a1x,a1y,a1z,a1w};
  *(float4*)&ctxbuf[((size_t)b*256+i0)*256 + 4*l] = o0;
  *(float4*)&ctxbuf[((size_t)b*256+i1)*256 + 4*l] = o1;
}

// ---------------- K8: projection + emissions (8 tokens / block) ----------------
__global__ __launch_bounds__(256) void k_proj_emit(
    const float* __restrict__ lstm_out, const float* __restrict__ ctxbuf,
    const float* __restrict__ pwT, const float* __restrict__ proj_b,
    const float* __restrict__ emit_w, const float* __restrict__ emit_b,
    float* __restrict__ em)
{
  __shared__ alignas(16) float attT[512*8];
  __shared__ alignas(16) float out8[8*260];
  int n0 = blockIdx.x*8, tid = threadIdx.x;
  for (int e=tid; e<4096; e+=256) {
    int d = e>>3, tok = e&7;
    int n = n0+tok;
    attT[e] = (d<256) ? lstm_out[(size_t)n*256 + d] : ctxbuf[(size_t)n*256 + d-256];
  }
  __syncthreads();
  int j = tid;
  {
    float acc[8];
    float bj = proj_b[j];
    #pragma unroll
    for (int t=0;t<8;t++) acc[t]=bj;
    for (int d=0; d<512; d++) {
      float w = pwT[d*256 + j];
      const float4 c0 = *(const float4*)&attT[d*8];
      const float4 c1 = *(const float4*)&attT[d*8+4];
      acc[0]+=w*c0.x; acc[1]+=w*c0.y; acc[2]+=w*c0.z; acc[3]+=w*c0.w;
      acc[4]+=w*c1.x; acc[5]+=w*c1.y; acc[6]+=w*c1.z; acc[7]+=w*c1.w;
    }
    #pragma unroll
    for (int t=0;t<8;t++) out8[t*260 + j] = acc[t];
  }
  __syncthreads();
  if (tid < 88) {
    int tok = tid/11, k = tid - tok*11;
    float acc = emit_b[k];
    for (int dc=0; dc<64; dc++) {
      const float4 o4 = *(const float4*)&out8[tok*260 + dc*4];
      const float4 w4 = *(const float4*)&emit_w[k*256 + dc*4];
      acc += o4.x*w4.x + o4.y*w4.y + o4.z*w4.z + o4.w*w4.w;
    }
    int n = n0+tok, bb = n>>8, tt = n&255;
    em[(tt*8+bb)*11 + k] = acc;
  }
}

// ---------------- K9: CRF NLL per batch (mask all-ones) ----------------
__global__ __launch_bounds__(64) void k_crf(
    const float* __restrict__ em, const int* __restrict__ tags,
    const float* __restrict__ trans, const float* __restrict__ cstart,
    const float* __restrict__ cend, float* __restrict__ nll)
{
  int b = blockIdx.x;
  int lane = threadIdx.x;
  float np = 0.f;
  for (int t=1+lane; t<256; t+=64) {
    int tp = tags[b*256 + t-1], tc = tags[b*256 + t];
    np += trans[tp*11+tc] + em[(t*8+b)*11 + tc];
  }
  #pragma unroll
  for (int off=1; off<64; off<<=1) np += __shfl_xor(np, off);
  int t0 = tags[b*256], tl = tags[b*256+255];
  float num = cstart[t0] + em[b*11 + t0] + np + cend[tl];
  int kq = lane>>4, kp = lane&15;
  float t3[3];
  #pragma unroll
  for (int r=0;r<3;r++) {
    int k = kq*3+r;
    t3[r] = (k<11 && kp<11) ? trans[k*11+kp] : 0.f;
  }
  float alpha = (kp<11) ? cstart[kp] + em[b*11 + kp] : -1e30f;
  float ecur = (kp<11) ? em[(8+b)*11 + kp] : 0.f;
  for (int t=1; t<256; t++) {
    float enext = (t<255 && kp<11) ? em[((t+1)*8+b)*11 + kp] : 0.f;
    float a0 = __shfl(alpha, 0);
    float p = 0.f;
    #pragma unroll
    for (int r=0;r<3;r++) {
      int k = kq*3+r;
      if (k<11 && kp<11) {
        float ak = __shfl(alpha, k);
        p += __expf(ak + t3[r] - a0);
      }
    }
    p += __shfl_xor(p, 16);
    p += __shfl_xor(p, 32);
    alpha = (kp<11) ? a0 + __logf(p) + ecur : -1e30f;
    ecur = enext;
  }
  float val = (kq==0 && kp<11) ? alpha + cend[kp] : -1e30f;
  float m = val;
  #pragma unroll
  for (int off=1; off<64; off<<=1) m = fmaxf(m, __shfl_xor(m, off));
  float ex = (kq==0 && kp<11) ? __expf(val-m) : 0.f;
  #pragma unroll
  for (int off=1; off<64; off<<=1) ex += __shfl_xor(ex, off);
  if (lane==0) nll[b] = (m + __logf(ex)) - num;
}

// ---------------- K10: mean over batch -> d_out ----------------
__global__ __launch_bounds__(64) void k_final(const float* __restrict__ nll, float* __restrict__ out)
{
  int lane = threadIdx.x;
  float v = (lane<8) ? nll[lane] : 0.f;
  #pragma unroll
  for (int off=1; off<64; off<<=1) v += __shfl_xor(v, off);
  if (lane==0) out[0] = v * 0.125f;
}

// ---------------- launch ----------------
extern "C" void kernel_launch(void* const* d_in, const int* in_sizes, int n_in,
                              void* d_out, int out_size, void* d_ws, size_t ws_size,
                              hipStream_t stream)
{
  const int* word_ids = (const int*)d_in[0];
  const int* char_ids = (const int*)d_in[1];
  const int* tags     = (const int*)d_in[3];
  const float* wtab   = (const float*)d_in[4];
  const float* ctab   = (const float*)d_in[5];
  const float* w3 = (const float*)d_in[6];  const float* b3 = (const float*)d_in[7];
  const float* w5 = (const float*)d_in[8];  const float* b5 = (const float*)d_in[9];
  const float* w7 = (const float*)d_in[10]; const float* b7 = (const float*)d_in[11];
  const float* lctab  = (const float*)d_in[12];
  const float* lwih_f = (const float*)d_in[13];
  const float* lwhh_f = (const float*)d_in[14];
  const float* lb_f   = (const float*)d_in[15];
  const float* cwih_f = (const float*)d_in[16];
  const float* cwhh_f = (const float*)d_in[17];
  const float* cb_f   = (const float*)d_in[18];
  const float* lwih_b = (const float*)d_in[19];
  const float* lwhh_b = (const float*)d_in[20];
  const float* lb_b   = (const float*)d_in[21];
  const float* cwih_b = (const float*)d_in[22];
  const float* cwhh_b = (const float*)d_in[23];
  const float* cb_b   = (const float*)d_in[24];
  const float* fusion_w = (const float*)d_in[25];
  const float* fusion_b = (const float*)d_in[26];
  const float* att_w  = (const float*)d_in[27];
  const float* proj_w = (const float*)d_in[28];
  const float* proj_b = (const float*)d_in[29];
  const float* emit_w = (const float*)d_in[30];
  const float* emit_b = (const float*)d_in[31];
  const float* trans  = (const float*)d_in[32];
  const float* cstart = (const float*)d_in[33];
  const float* cend   = (const float*)d_in[34];

  float* ws = (float*)d_ws;
  float* cnn_feat  = ws + O_CNN;
  float* clstm_feat= ws + O_CLSTM;
  float* fused     = ws + O_FUSED;
  float* xg2       = ws + O_XG2;
  float* lstm_out  = ws + O_LSTM;
  float* wjv       = ws + O_WJ;
  float* ctxb      = ws + O_CTXB;
  float* emv       = ws + O_EM;
  float* nllv      = ws + O_NLL;
  float* fwT       = ws + O_FWT;
  float* cwihT     = ws + O_CWIHT;
  float* cwhhT     = ws + O_CWHHT;
  float* lwihT     = ws + O_LWIHT;
  float* lwhhT     = ws + O_LWHHT;
  float* pwT       = ws + O_PWT;
  float* w3T       = ws + O_W3T;
  float* w5T       = ws + O_W5T;
  float* w7T       = ws + O_W7T;

  k_transpose<<<2384,256,0,stream>>>(fusion_w, cwih_f, cwih_b, cwhh_f, cwhh_b,
                                     lwih_f, lwih_b, lwhh_f, lwhh_b, proj_w,
                                     w3, w5, w7,
                                     fwT, cwihT, cwhhT, lwihT, lwhhT, pwT,
                                     w3T, w5T, w7T);
  k_charcnn<<<2048,384,0,stream>>>(char_ids, ctab, w3T,b3,w5T,b5,w7T,b7, cnn_feat);
  k_charlstm<<<dim3(2048,2),256,0,stream>>>(char_ids, lctab, lwihT, lwhhT, lb_f, lb_b, clstm_feat);
  k_fusion<<<256,256,0,stream>>>(word_ids, wtab, cnn_feat, clstm_feat, fwT, fusion_b, fused);
  k_ctxxg<<<256,256,0,stream>>>(fused, cwihT, cb_f, cb_b, xg2);
  k_ctxlstm<<<16,512,0,stream>>>(xg2, cwhhT, lstm_out);
  k_wj<<<512,256,0,stream>>>(lstm_out, att_w, wjv);
  k_attention<<<dim3(32,8),256,0,stream>>>(lstm_out, wjv, ctxb);
  k_proj_emit<<<256,256,0,stream>>>(lstm_out, ctxb, pwT, proj_b, emit_w, emit_b, emv);
  k_crf<<<8,64,0,stream>>>(emv, tags, trans, cstart, cend, nllv);
  k_final<<<1,64,0,stream>>>(nllv, (float*)d_out);
}